// Round 2
// baseline (964.917 us; speedup 1.0000x reference)
//
#include <hip/hip_runtime.h>

// Problem constants: B=2048, F=64, R=32, P=16, C=128, TAU=2.0
#define B_ 2048

typedef unsigned short u16;
typedef unsigned int   u32;

__device__ __forceinline__ float bfu(u16 u) {
    u32 i = ((u32)u) << 16; float f; __builtin_memcpy(&f, &i, 4); return f;
}
__device__ __forceinline__ float bflo(u32 w) {
    u32 i = w << 16; float f; __builtin_memcpy(&f, &i, 4); return f;
}
__device__ __forceinline__ float bfhi(u32 w) {
    u32 i = w & 0xffff0000u; float f; __builtin_memcpy(&f, &i, 4); return f;
}
__device__ __forceinline__ u16 f2bf(float v) {
    u32 iv; __builtin_memcpy(&iv, &v, 4);
    u32 r = (iv + 0x7fffu + ((iv >> 16) & 1u)) >> 16;
    return (u16)r;
}
__device__ __forceinline__ float sigm(float x) { return 1.f / (1.f + __expf(-x)); }
__device__ __forceinline__ float lsg(float x) {
    return fminf(x, 0.f) - log1pf(__expf(-fabsf(x)));
}

// dtype-dispatched loads (element-indexed; bf16 paths match 4B/8B vector loads)
template<bool F32> __device__ __forceinline__ float LD(const void* p, int e) {
    if (F32) return ((const float*)p)[e];
    return bfu(((const u16*)p)[e]);
}
template<bool F32> __device__ __forceinline__ float2 LD2(const void* p, int e) { // e even
    if (F32) { const float* q = (const float*)p; return make_float2(q[e], q[e + 1]); }
    u32 w = ((const u32*)p)[e >> 1];
    return make_float2(bflo(w), bfhi(w));
}
template<bool F32> __device__ __forceinline__ float4 LD4(const void* p, int e) { // e%4==0
    if (F32) return ((const float4*)p)[e >> 2];
    uint2 w = ((const uint2*)p)[e >> 2];
    return make_float4(bflo(w.x), bfhi(w.x), bflo(w.y), bfhi(w.y));
}
template<bool F32> __device__ __forceinline__ void ST(void* p, int e, float v) {
    if (F32) ((float*)p)[e] = v; else ((u16*)p)[e] = f2bf(v);
}

struct Smem {
    // Union region U: phases A-C use c/modl/Wk/bk; phase C2+ overlays xtab[6144]
    float U[6144];
    float form_s[64 * 33];   // [f][r], pitch 33
    float match_s[512];      // [p][r]
    float wch_s[1024];       // [p][f] (mod-scaled)
    float vch_s[1024];       // [p][f]
    float vep0_s[1024];      // [p][f]
    float vep2_s[1024];      // [p][f]
    float wep0_s[16], wep2_s[16], wdl_s[16];
    float wnc_s[64];
    float sc_s[2];           // {w_nodeln, w_noepen}
    float ssum_s[96];        // [which(0:ep0,1:ep2,2:deln)][rs]
};

struct Args {
    const void *form, *ctx;
    const void *mod_W, *mod_b, *wch_W, *wch_b, *wdl_W, *wdl_b, *wep_W, *wep_b;
    const void *vch_W, *vch_b, *vep_W, *vep_b;
    const void *wnc_W, *wnc_b, *wnd_W, *wnd_b, *wne_W, *wne_b;
    const void *m_W, *m_Wb, *mb_W, *mb_b;
    void* outp;
};

template<bool F32>
__device__ void body(Smem& S, int t, int b, const Args& A) {
    float* c_s  = S.U;            // 128
    float* modl = S.U + 128;      // 96
    float* Wk_s = S.U + 224;      // 48*65 (pitch 65)
    float* bk_s = S.U + 3344;     // 48
    float* xtab = S.U;            // phase C2+: [sub][rs][f] = 3*32*64

    // ---------------- Phase A: context row + form tile ----------------
    if (t < 128) c_s[t] = LD<F32>(A.ctx, b * 128 + t);
    {
        int e0 = b * 2048 + t * 8;
        float4 x = LD4<F32>(A.form, e0);
        float4 y = LD4<F32>(A.form, e0 + 4);
        int f = t >> 2, r0 = (t & 3) * 8;
        float* dst = S.form_s + f * 33 + r0;
        dst[0] = x.x; dst[1] = x.y; dst[2] = x.z; dst[3] = x.w;
        dst[4] = y.x; dst[5] = y.y; dst[6] = y.z; dst[7] = y.w;
    }
    __syncthreads();

    // ---------------- Phase B1: mod lin + softmax(6) ----------------
    if (t < 96) {
        float a = LD<F32>(A.mod_b, t);
        for (int cc = 0; cc < 128; ++cc) a += c_s[cc] * LD<F32>(A.mod_W, cc * 96 + t);
        modl[t] = a;
    }
    __syncthreads();
    if (t < 16) {
        float v[6]; float mx = -1e30f;
        #pragma unroll
        for (int j = 0; j < 6; ++j) { v[j] = modl[t * 6 + j]; mx = fmaxf(mx, v[j]); }
        float s = 0.f;
        #pragma unroll
        for (int j = 0; j < 6; ++j) { v[j] = __expf(v[j] - mx); s += v[j]; }
        float inv = 1.f / s;
        #pragma unroll
        for (int j = 0; j < 6; ++j) modl[t * 6 + j] = v[j] * inv;
    }
    __syncthreads();

    // ---------------- Phase B2: all other linear columns ----------------
    for (int j = t; j < 512; j += 256) {          // wch, N=1024 paired cols
        int n0 = j * 2;
        float2 bb = LD2<F32>(A.wch_b, n0);
        float a0 = bb.x, a1 = bb.y;
        for (int cc = 0; cc < 128; ++cc) {
            float2 w = LD2<F32>(A.wch_W, cc * 1024 + n0); float cv = c_s[cc];
            a0 += cv * w.x; a1 += cv * w.y;
        }
        int p = n0 >> 6; float sc = modl[p * 6 + 0];
        S.wch_s[n0] = sc * a0; S.wch_s[n0 + 1] = sc * a1;
    }
    for (int j = t; j < 512; j += 256) {          // vch, N=1024
        int n0 = j * 2;
        float2 bb = LD2<F32>(A.vch_b, n0);
        float a0 = bb.x, a1 = bb.y;
        for (int cc = 0; cc < 128; ++cc) {
            float2 w = LD2<F32>(A.vch_W, cc * 1024 + n0); float cv = c_s[cc];
            a0 += cv * w.x; a1 += cv * w.y;
        }
        S.vch_s[n0] = a0; S.vch_s[n0 + 1] = a1;
    }
    for (int u = t; u < 1024; u += 256) {         // vep, N=4096; keep e=0 and e=2
        int n0 = u * 4;
        float4 bb = LD4<F32>(A.vep_b, n0);
        float a0 = bb.x, a2 = bb.z;
        for (int cc = 0; cc < 128; ++cc) {
            float4 w = LD4<F32>(A.vep_W, cc * 4096 + n0); float cv = c_s[cc];
            a0 += cv * w.x; a2 += cv * w.z;
        }
        S.vep0_s[u] = a0; S.vep2_s[u] = a2;
    }
    for (int j = t; j < 1536; j += 256) {         // m_W (3,128,1024)
        int k  = j >> 9;
        int jj = j & 511;
        int n0 = jj * 2;
        float2 bb = LD2<F32>(A.m_Wb, k * 1024 + n0);
        float a0 = bb.x, a1 = bb.y;
        for (int cc = 0; cc < 128; ++cc) {
            float2 w = LD2<F32>(A.m_W, (k * 128 + cc) * 1024 + n0); float cv = c_s[cc];
            a0 += cv * w.x; a1 += cv * w.y;
        }
        int p = n0 >> 6, f = n0 & 63;
        Wk_s[(k * 16 + p) * 65 + f]     = a0;
        Wk_s[(k * 16 + p) * 65 + f + 1] = a1;
    }
    if (t < 16) {                                  // wep cols 4t..4t+3; use e=0,2
        int n0 = t * 4;
        float4 bb = LD4<F32>(A.wep_b, n0);
        float a0 = bb.x, a2 = bb.z;
        for (int cc = 0; cc < 128; ++cc) {
            float4 w = LD4<F32>(A.wep_W, cc * 64 + n0); float cv = c_s[cc];
            a0 += cv * w.x; a2 += cv * w.z;
        }
        S.wep0_s[t] = modl[t * 6 + 2] * a0;        // mod[...,2+0]
        S.wep2_s[t] = modl[t * 6 + 4] * a2;        // mod[...,2+2]
    } else if (t < 32) {
        int p = t - 16;
        float a = LD<F32>(A.wdl_b, p);
        for (int cc = 0; cc < 128; ++cc) a += c_s[cc] * LD<F32>(A.wdl_W, cc * 16 + p);
        S.wdl_s[p] = modl[p * 6 + 1] * a;
    } else if (t < 96) {
        int f = t - 32;
        float a = LD<F32>(A.wnc_b, f);
        for (int cc = 0; cc < 128; ++cc) a += c_s[cc] * LD<F32>(A.wnc_W, cc * 64 + f);
        S.wnc_s[f] = __expf(a);                    // w_nochng
    } else if (t < 98) {
        const void* W  = (t == 96) ? A.wnd_W : A.wne_W;
        const void* bb = (t == 96) ? A.wnd_b : A.wne_b;
        float a = LD<F32>(bb, 0);
        for (int cc = 0; cc < 128; ++cc) a += c_s[cc] * LD<F32>(W, cc);
        S.sc_s[t - 96] = __expf(a);                // [0]=w_nodeln, [1]=w_noepen
    } else if (t < 146) {
        int i = t - 98;                            // 48 bk entries, i = k*16+p
        int k = i >> 4, p = i & 15;
        float a = LD<F32>(A.mb_b, k * 16 + p);
        for (int cc = 0; cc < 128; ++cc) a += c_s[cc] * LD<F32>(A.mb_W, (k * 128 + cc) * 16 + p);
        bk_s[i] = a;
    }
    __syncthreads();

    // ---------------- Phase C: match[p][r] ----------------
    for (int idx = t; idx < 512; idx += 256) {
        int p = idx >> 5, r = idx & 31;
        float s0 = bk_s[p], s1 = bk_s[16 + p], s2 = bk_s[32 + p];
        const float* w0 = Wk_s + p * 65;
        const float* w1 = Wk_s + (16 + p) * 65;
        const float* w2 = Wk_s + (32 + p) * 65;
        for (int f = 0; f < 64; ++f) {
            const float* fr = S.form_s + f * 33 + r;
            float fm1 = (r > 0)  ? fr[-1] : 0.f;   // prev
            float f0  = fr[0];                     // cur
            float fp1 = (r < 31) ? fr[1]  : 0.f;   // next
            s0 += w0[f] * fm1; s1 += w1[f] * f0; s2 += w2[f] * fp1;
        }
        S.match_s[p * 32 + r] = __expf(lsg(s0) + lsg(s1) + lsg(s2));
    }
    __syncthreads();

    // ---------------- Phase C2: ssum + xtab (overlays U) ----------------
    if (t < 96) {
        int which = t >> 5, r = t & 31;
        const float* w = (which == 0) ? S.wep0_s : (which == 1) ? S.wep2_s : S.wdl_s;
        float s = 0.f;
        for (int p = 0; p < 16; ++p) s += S.match_s[p * 32 + r] * w[p];
        S.ssum_s[which * 32 + r] = s;
    }
    #pragma unroll 1
    for (int q = 0; q < 24; ++q) {
        int idx = t + 256 * q;                     // idx = sub*2048 + rs*64 + f
        int sub = idx >> 11;
        int rs  = (idx >> 6) & 31;
        int f   = idx & 63;
        float x;
        if (sub == 1) {
            float sum = 0.f, vs = 0.f;
            for (int p = 0; p < 16; ++p) {
                float wc = S.match_s[p * 32 + rs] * S.wch_s[p * 64 + f];
                sum += wc;
                vs  += fmaxf(wc, 0.f) * S.vch_s[p * 64 + f];
            }
            float pch = sigm(sum - S.wnc_s[f]);
            float si  = S.form_s[f * 33 + rs];
            x = si + pch * (vs - si);              // sym
        } else {
            const float* wep = (sub == 0) ? S.wep0_s : S.wep2_s;
            const float* vep = (sub == 0) ? S.vep0_s : S.vep2_s;
            float vs = 0.f;
            for (int p = 0; p < 16; ++p) {
                float w = S.match_s[p * 32 + rs] * wep[p];
                vs += fmaxf(w, 0.f) * vep[p * 64 + f];
            }
            x = vs;                                // v
        }
        xtab[idx] = x;
    }
    __syncthreads();

    // ---------------- Phase D: barrier-free sequential scan ----------------
    const int my_r = t & 31;
    const int fgrp = t >> 5;
    float oreg[8];
    #pragma unroll
    for (int i = 0; i < 8; ++i) oreg[i] = 0.f;
    float posn = 0.f;
    const float wnd1v = S.sc_s[0];   // w_nodeln
    const float wne1v = S.sc_s[1];   // w_noepen

    for (int rs = 0; rs < 32; ++rs) {
        #pragma unroll
        for (int sub = 0; sub < 3; ++sub) {
            float coef;
            if (sub == 1) coef = 1.f - sigm(S.ssum_s[64 + rs] - wnd1v);         // 1-p_deln
            else          coef = sigm(S.ssum_s[(sub & 2) * 16 + rs] - wne1v);   // p_epen
            // windowed softmax of -2*(posn-r)^2 (±4 around clamped-nearest int;
            // truncated mass <= e^-24.5, far below tolerance). Z >= 1 always.
            float pc = fminf(posn, 31.f);
            int ci = (int)(pc + 0.5f);
            int lo = ci - 4; if (lo < 0)  lo = 0;
            int hi = ci + 4; if (hi > 31) hi = 31;
            float dmin = posn - (float)ci;
            float mx = -2.f * dmin * dmin;
            float Z = 0.f, eo = 0.f;
            for (int r = lo; r <= hi; ++r) {
                float d = posn - (float)r;
                float e = __expf(-2.f * d * d - mx);
                Z += e;
                if (r == my_r) eo = e;
            }
            float g = coef * eo / Z;
            const float* xb = xtab + (sub * 2048 + rs * 64 + fgrp * 8);
            #pragma unroll
            for (int i = 0; i < 8; ++i) oreg[i] += g * (xb[i] - oreg[i]);
            posn += coef;
        }
    }

    // ---------------- Phase E: store out[b][f][r] ----------------
    #pragma unroll
    for (int i = 0; i < 8; ++i) {
        ST<F32>(A.outp, b * 2048 + (fgrp * 8 + i) * 32 + my_r, oreg[i]);
    }
}

__global__ __launch_bounds__(256) void phon_kernel(Args A) {
    __shared__ Smem S;
    __shared__ int dt_s;
    const int t = threadIdx.x, b = blockIdx.x;

    // dtype probe on context row 0 (block-uniform): for true-bf16 data the
    // even-position u16s are sane bf16 (exponent near bias); for fp32 data
    // they are mantissa garbage (~12% sane). Deterministic, same every call.
    if (t == 0) {
        int sane = 0;
        const u16* q = (const u16*)A.ctx;
        for (int i = 0; i < 64; ++i) {
            u16 u = q[2 * i];
            int ex = (u >> 7) & 0xFF;
            sane += (u == 0 || (ex >= 112 && ex <= 143)) ? 1 : 0;
        }
        dt_s = (sane < 32) ? 1 : 0;   // 1 => fp32
    }
    __syncthreads();
    if (dt_s) body<true>(S, t, b, A);
    else      body<false>(S, t, b, A);
}

extern "C" void kernel_launch(void* const* d_in, const int* in_sizes, int n_in,
                              void* d_out, int out_size, void* d_ws, size_t ws_size,
                              hipStream_t stream) {
    Args A;
    A.form  = d_in[0];  A.ctx   = d_in[1];
    A.mod_W = d_in[2];  A.mod_b = d_in[3];
    A.wch_W = d_in[4];  A.wch_b = d_in[5];
    A.wdl_W = d_in[6];  A.wdl_b = d_in[7];
    A.wep_W = d_in[8];  A.wep_b = d_in[9];
    A.vch_W = d_in[10]; A.vch_b = d_in[11];
    A.vep_W = d_in[12]; A.vep_b = d_in[13];
    A.wnc_W = d_in[14]; A.wnc_b = d_in[15];
    A.wnd_W = d_in[16]; A.wnd_b = d_in[17];
    A.wne_W = d_in[18]; A.wne_b = d_in[19];
    A.m_W   = d_in[20]; A.m_Wb  = d_in[21];
    A.mb_W  = d_in[22]; A.mb_b  = d_in[23];
    A.outp  = d_out;

    phon_kernel<<<B_, 256, 0, stream>>>(A);
}

// Round 3
// 629.670 us; speedup vs baseline: 1.5324x; 1.5324x over previous
//
#include <hip/hip_runtime.h>

// Problem constants: B=2048, F=64, R=32, P=16, C=128, TAU=2.0
#define B_ 2048
#define NTOT 7426
#define YSTRIDE 7432

typedef unsigned short u16;
typedef unsigned int   u32;
typedef __attribute__((ext_vector_type(2))) float v2f;

__device__ __forceinline__ float bfu(u16 u) {
    u32 i = ((u32)u) << 16; float f; __builtin_memcpy(&f, &i, 4); return f;
}
__device__ __forceinline__ float bflo(u32 w) {
    u32 i = w << 16; float f; __builtin_memcpy(&f, &i, 4); return f;
}
__device__ __forceinline__ float bfhi(u32 w) {
    u32 i = w & 0xffff0000u; float f; __builtin_memcpy(&f, &i, 4); return f;
}
__device__ __forceinline__ u16 f2bf(float v) {
    u32 iv; __builtin_memcpy(&iv, &v, 4);
    u32 r = (iv + 0x7fffu + ((iv >> 16) & 1u)) >> 16;
    return (u16)r;
}
__device__ __forceinline__ float sigm(float x) { return 1.f / (1.f + __expf(-x)); }
__device__ __forceinline__ float lsg(float x) {
    return fminf(x, 0.f) - log1pf(__expf(-fabsf(x)));
}

template<bool F32> __device__ __forceinline__ float LD(const void* p, int e) {
    if (F32) return ((const float*)p)[e];
    return bfu(((const u16*)p)[e]);
}
template<bool F32> __device__ __forceinline__ float2 LD2(const void* p, int e) { // e even
    if (F32) { const float* q = (const float*)p; return make_float2(q[e], q[e + 1]); }
    u32 w = ((const u32*)p)[e >> 1];
    return make_float2(bflo(w), bfhi(w));
}
template<bool F32> __device__ __forceinline__ float4 LD4(const void* p, int e) { // e%4==0
    if (F32) return ((const float4*)p)[e >> 2];
    uint2 w = ((const uint2*)p)[e >> 2];
    return make_float4(bflo(w.x), bfhi(w.x), bflo(w.y), bfhi(w.y));
}
template<bool F32> __device__ __forceinline__ void ST(void* p, int e, float v) {
    if (F32) ((float*)p)[e] = v; else ((u16*)p)[e] = f2bf(v);
}

struct Args {
    const void *form, *ctx;
    const void *mod_W, *mod_b, *wch_W, *wch_b, *wdl_W, *wdl_b, *wep_W, *wep_b;
    const void *vch_W, *vch_b, *vep_W, *vep_b;
    const void *wnc_W, *wnc_b, *wnd_W, *wnd_b, *wne_W, *wne_b;
    const void *m_W, *m_Wb, *mb_W, *mb_b;
    void* outp;
};

// dtype probe: block-uniform, deterministic. Returns 1 if inputs are fp32.
template<bool DUMMY>
__device__ __forceinline__ int probe_is_f32(const void* ctx, int t, int* flag_s) {
    if (t == 0) {
        int sane = 0;
        const u16* q = (const u16*)ctx;
        for (int i = 0; i < 64; ++i) {
            u16 u = q[2 * i];
            int ex = (u >> 7) & 0xFF;
            sane += (u == 0 || (ex >= 112 && ex <= 143)) ? 1 : 0;
        }
        *flag_s = (sane < 32) ? 1 : 0;
    }
    __syncthreads();
    return *flag_s;
}

// ============================================================================
// Kernel 1: compacted-column GEMM  Y[b][n] = ctx[b] . Wcat[:,n] + bcat[n]
// Column layout (NTOT=7426):
//  [0,96)    mod       [96,1120)  wch       [1120,2144) vch
//  [2144,4192) vepI (interleaved e0/e2: 2u->vep col 4u, 2u+1->4u+2)
//  [4192,7264) Wk (k*1024 + p*64 + f)       [7264,7312) bk (k*16+p)
//  [7312,7344) wepI (2t->wep col 4t, 2t+1->4t+2)
//  [7344,7360) wdl   [7360,7424) wnc   [7424] wnd   [7425] wne
// ============================================================================
struct PD { const void* p0; int off; int st; int mode; float b0, b1; };

template<bool F32>
__device__ __forceinline__ void resolve(const Args& A, int n0, PD& d) {
    if (n0 < 96) {
        d.mode = 0; d.p0 = A.mod_W; d.off = n0; d.st = 96;
        float2 b = LD2<F32>(A.mod_b, n0); d.b0 = b.x; d.b1 = b.y;
    } else if (n0 < 1120) {
        int j = n0 - 96;
        d.mode = 0; d.p0 = A.wch_W; d.off = j; d.st = 1024;
        float2 b = LD2<F32>(A.wch_b, j); d.b0 = b.x; d.b1 = b.y;
    } else if (n0 < 2144) {
        int j = n0 - 1120;
        d.mode = 0; d.p0 = A.vch_W; d.off = j; d.st = 1024;
        float2 b = LD2<F32>(A.vch_b, j); d.b0 = b.x; d.b1 = b.y;
    } else if (n0 < 4192) {
        int u = (n0 - 2144) >> 1;
        d.mode = 1; d.p0 = A.vep_W; d.off = 4 * u; d.st = 4096;
        float4 b = LD4<F32>(A.vep_b, 4 * u); d.b0 = b.x; d.b1 = b.z;
    } else if (n0 < 7264) {
        int i = n0 - 4192; int k = i >> 10, j = i & 1023;
        d.mode = 0; d.p0 = A.m_W; d.off = k * 131072 + j; d.st = 1024;
        float2 b = LD2<F32>(A.m_Wb, k * 1024 + j); d.b0 = b.x; d.b1 = b.y;
    } else if (n0 < 7312) {
        int i = n0 - 7264; int k = i >> 4, p = i & 15;
        d.mode = 0; d.p0 = A.mb_W; d.off = k * 2048 + p; d.st = 16;
        float2 b = LD2<F32>(A.mb_b, k * 16 + p); d.b0 = b.x; d.b1 = b.y;
    } else if (n0 < 7344) {
        int u = (n0 - 7312) >> 1;
        d.mode = 1; d.p0 = A.wep_W; d.off = 4 * u; d.st = 64;
        float4 b = LD4<F32>(A.wep_b, 4 * u); d.b0 = b.x; d.b1 = b.z;
    } else if (n0 < 7360) {
        int j = n0 - 7344;
        d.mode = 0; d.p0 = A.wdl_W; d.off = j; d.st = 16;
        float2 b = LD2<F32>(A.wdl_b, j); d.b0 = b.x; d.b1 = b.y;
    } else if (n0 < 7424) {
        int j = n0 - 7360;
        d.mode = 0; d.p0 = A.wnc_W; d.off = j; d.st = 64;
        float2 b = LD2<F32>(A.wnc_b, j); d.b0 = b.x; d.b1 = b.y;
    } else if (n0 == 7424) {
        d.mode = 2; d.p0 = A.wnd_W; d.off = 0; d.st = 1;
        d.b0 = LD<F32>(A.wnd_b, 0); d.b1 = LD<F32>(A.wne_b, 0);
    } else {
        d.mode = 3; d.p0 = A.mod_W; d.off = 0; d.st = 0; d.b0 = 0.f; d.b1 = 0.f;
    }
}

template<bool F32>
__device__ __forceinline__ v2f fetchw(const PD& d, const Args& A, int c) {
    if (d.mode == 0) {
        float2 w = LD2<F32>(d.p0, d.off + c * d.st);
        v2f r; r.x = w.x; r.y = w.y; return r;
    } else if (d.mode == 1) {
        float4 q = LD4<F32>(d.p0, d.off + c * d.st);
        v2f r; r.x = q.x; r.y = q.z; return r;
    } else if (d.mode == 2) {
        v2f r; r.x = LD<F32>(A.wnd_W, c); r.y = LD<F32>(A.wne_W, c); return r;
    }
    v2f r; r.x = 0.f; r.y = 0.f; return r;
}

template<bool F32>
__device__ void gemm_body(float (*ctx_s)[128], int t, int blk, const Args& A, float* Y) {
    const int cb = blk & 3;          // col-block (0..3), 2048 cols each
    const int bb = blk >> 2;         // batch-block (0..255), 8 batches each
    const int mb = bb * 8;

    // stage ctx tile [8][128]
    {
        int m = t >> 5, c0 = (t & 31) * 4;
        float4 v = LD4<F32>(A.ctx, (mb + m) * 128 + c0);
        ctx_s[m][c0] = v.x; ctx_s[m][c0 + 1] = v.y; ctx_s[m][c0 + 2] = v.z; ctx_s[m][c0 + 3] = v.w;
    }
    __syncthreads();

    PD d[4]; int n0[4];
    #pragma unroll
    for (int i = 0; i < 4; ++i) {
        n0[i] = cb * 2048 + i * 512 + 2 * t;
        resolve<F32>(A, n0[i], d[i]);
    }
    v2f acc[4][8];
    #pragma unroll
    for (int i = 0; i < 4; ++i)
        #pragma unroll
        for (int m = 0; m < 8; ++m) { acc[i][m].x = d[i].b0; acc[i][m].y = d[i].b1; }

    for (int c4 = 0; c4 < 32; ++c4) {
        float cv[8][4];
        #pragma unroll
        for (int m = 0; m < 8; ++m) *(float4*)cv[m] = *(const float4*)&ctx_s[m][c4 * 4];
        #pragma unroll
        for (int j = 0; j < 4; ++j) {
            int c = c4 * 4 + j;
            v2f w[4];
            #pragma unroll
            for (int i = 0; i < 4; ++i) w[i] = fetchw<F32>(d[i], A, c);
            #pragma unroll
            for (int m = 0; m < 8; ++m) {
                float cs = cv[m][j];
                v2f cvv; cvv.x = cs; cvv.y = cs;
                #pragma unroll
                for (int i = 0; i < 4; ++i) acc[i][m] += cvv * w[i];
            }
        }
    }

    #pragma unroll
    for (int i = 0; i < 4; ++i) {
        if (d[i].mode < 3) {
            #pragma unroll
            for (int m = 0; m < 8; ++m) {
                float2 s; s.x = acc[i][m].x; s.y = acc[i][m].y;
                *(float2*)(Y + (size_t)(mb + m) * YSTRIDE + n0[i]) = s;
            }
        }
    }
}

__global__ __launch_bounds__(256) void gemm_kernel(Args A, float* Y) {
    __shared__ float ctx_s[8][128];
    __shared__ int dt_s;
    const int t = threadIdx.x, blk = blockIdx.x;
    int isf32 = probe_is_f32<true>(A.ctx, t, &dt_s);
    if (isf32) gemm_body<true>(ctx_s, t, blk, A, Y);
    else       gemm_body<false>(ctx_s, t, blk, A, Y);
}

// ============================================================================
// Kernel 2: per-batch match + xtab + sequential scan, reading precomputed Y row
// ============================================================================
struct __align__(16) ScanSmem {
    float U[6144];          // phases B-C: Wk_s(3072 pitch64) bk(48) modl(96); C2+: xtab
    float form_s[64 * 33];  // [f][r] pitch 33
    float match_s[512];     // [p][r]
    float wch_s[1024];      // [p][f] (mod-scaled after softmax)
    float vch_s[1024];
    float vepI_s[2048];     // interleaved: [2*(p*64+f)+{0:e0,1:e2}]
    float wnc_s[64];
    float wep0_s[16], wep2_s[16], wdl_s[16];
    float coef_s[96];       // [sub][rs]
    float sc_s[2];          // {w_nodeln, w_noepen}
};

template<bool F32>
__device__ void scan_body(ScanSmem& S, int t, int b, const Args& A, const float* __restrict__ Y) {
    float* Wk_s = S.U;            // 48 rows x 64 (pitch 64; reads are broadcast)
    float* bk_s = S.U + 3072;     // 48
    float* modl = S.U + 3120;     // 96
    float* xtab = S.U;            // overlay after phase C

    const float* Yr = Y + (size_t)b * YSTRIDE;
    const float4* Y4 = (const float4*)Yr;

    // ---- stage form tile ----
    {
        int e0 = b * 2048 + t * 8;
        float4 x = LD4<F32>(A.form, e0);
        float4 y = LD4<F32>(A.form, e0 + 4);
        int f = t >> 2, r0 = (t & 3) * 8;
        float* dst = S.form_s + f * 33 + r0;
        dst[0] = x.x; dst[1] = x.y; dst[2] = x.z; dst[3] = x.w;
        dst[4] = y.x; dst[5] = y.y; dst[6] = y.z; dst[7] = y.w;
    }
    // ---- stage Y row segments ----
    for (int i = t; i < 768; i += 256) ((float4*)Wk_s)[i] = Y4[1048 + i];   // Wk @4192
    if (t < 12) ((float4*)bk_s)[t] = Y4[1816 + t];                          // bk @7264
    if (t < 24) ((float4*)modl)[t] = Y4[t];                                 // mod @0
    ((float4*)S.wch_s)[t] = Y4[24 + t];                                     // wch @96
    ((float4*)S.vch_s)[t] = Y4[280 + t];                                    // vch @1120
    for (int i = t; i < 512; i += 256) ((float4*)S.vepI_s)[i] = Y4[536 + i];// vepI @2144
    if (t < 16) {
        S.wep0_s[t] = Yr[7312 + 2 * t];
        S.wep2_s[t] = Yr[7312 + 2 * t + 1];
        S.wdl_s[t]  = Yr[7344 + t];
    } else if (t >= 32 && t < 96) {
        S.wnc_s[t - 32] = __expf(Yr[7360 + (t - 32)]);
    } else if (t >= 96 && t < 98) {
        S.sc_s[t - 96] = __expf(Yr[7424 + (t - 96)]);
    }
    __syncthreads();

    // ---- softmax(6) on mod ----
    if (t < 16) {
        float v[6]; float mx = -1e30f;
        #pragma unroll
        for (int j = 0; j < 6; ++j) { v[j] = modl[t * 6 + j]; mx = fmaxf(mx, v[j]); }
        float s = 0.f;
        #pragma unroll
        for (int j = 0; j < 6; ++j) { v[j] = __expf(v[j] - mx); s += v[j]; }
        float inv = 1.f / s;
        #pragma unroll
        for (int j = 0; j < 6; ++j) modl[t * 6 + j] = v[j] * inv;
    }
    __syncthreads();

    // ---- mod scaling + phase C (match) ----
    if (t < 16) {
        S.wep0_s[t] *= modl[t * 6 + 2];
        S.wep2_s[t] *= modl[t * 6 + 4];
        S.wdl_s[t]  *= modl[t * 6 + 1];
    }
    for (int i = t; i < 1024; i += 256) S.wch_s[i] *= modl[(i >> 6) * 6];

    const int my_r = t & 31;
    #pragma unroll 1
    for (int it = 0; it < 2; ++it) {
        int idx = t + 256 * it;
        int p = idx >> 5, r = idx & 31;
        float s0 = bk_s[p], s1 = bk_s[16 + p], s2 = bk_s[32 + p];
        const float4* w0 = (const float4*)(Wk_s + p * 64);
        const float4* w1 = (const float4*)(Wk_s + (16 + p) * 64);
        const float4* w2 = (const float4*)(Wk_s + (32 + p) * 64);
        for (int f4 = 0; f4 < 16; ++f4) {
            float a0[4], a1[4], a2[4];
            *(float4*)a0 = w0[f4]; *(float4*)a1 = w1[f4]; *(float4*)a2 = w2[f4];
            #pragma unroll
            for (int j = 0; j < 4; ++j) {
                int f = f4 * 4 + j;
                float f0 = S.form_s[f * 33 + r];
                float fm = __shfl_up(f0, 1, 32);   if (r == 0)  fm = 0.f;
                float fp = __shfl_down(f0, 1, 32); if (r == 31) fp = 0.f;
                s0 += a0[j] * fm; s1 += a1[j] * f0; s2 += a2[j] * fp;
            }
        }
        S.match_s[p * 32 + r] = __expf(lsg(s0) + lsg(s1) + lsg(s2));
    }
    __syncthreads();

    // ---- phase C2: coef + xtab (xtab overlays U; Wk/bk/mod dead) ----
    if (t < 96) {
        int sub = t >> 5, r = t & 31;
        const float* w = (sub == 0) ? S.wep0_s : (sub == 1) ? S.wdl_s : S.wep2_s;
        float s = 0.f;
        for (int p = 0; p < 16; ++p) s += S.match_s[p * 32 + r] * w[p];
        float cf;
        if (sub == 1) cf = 1.f - sigm(s - S.sc_s[0]);   // 1 - p_deln
        else          cf = sigm(s - S.sc_s[1]);         // p_epen
        S.coef_s[sub * 32 + r] = cf;
    }
    #pragma unroll 1
    for (int q = 0; q < 24; ++q) {
        int idx = t + 256 * q;                     // idx = sub*2048 + rs*64 + f
        int sub = idx >> 11;
        int rs  = (idx >> 6) & 31;
        int f   = idx & 63;
        float x;
        if (sub == 1) {
            float sum = 0.f, vs = 0.f;
            for (int p = 0; p < 16; ++p) {
                float wc = S.match_s[p * 32 + rs] * S.wch_s[p * 64 + f];
                sum += wc;
                vs  += fmaxf(wc, 0.f) * S.vch_s[p * 64 + f];
            }
            float pch = sigm(sum - S.wnc_s[f]);
            float si  = S.form_s[f * 33 + rs];
            x = si + pch * (vs - si);              // sym
        } else {
            const float* wep = (sub == 0) ? S.wep0_s : S.wep2_s;
            int s1i = (sub == 0) ? 0 : 1;
            float vs = 0.f;
            for (int p = 0; p < 16; ++p) {
                float w = S.match_s[p * 32 + rs] * wep[p];
                vs += fmaxf(w, 0.f) * S.vepI_s[2 * (p * 64 + f) + s1i];
            }
            x = vs;
        }
        xtab[idx] = x;
    }
    __syncthreads();

    // ---- phase D: barrier-free scan; softmax via 1 exp + wave reduce ----
    const int fgrp = t >> 5;
    float oreg[8];
    #pragma unroll
    for (int i = 0; i < 8; ++i) oreg[i] = 0.f;
    float posn = 0.f;

    for (int rs = 0; rs < 32; ++rs) {
        #pragma unroll
        for (int sub = 0; sub < 3; ++sub) {
            float coef = S.coef_s[sub * 32 + rs];
            // softmax_r(-2 (posn-r)^2), exact with max subtraction
            float pc = fminf(posn, 31.f);
            float ci = floorf(pc + 0.5f);
            float dmin = posn - ci;
            float dd = posn - (float)my_r;
            float eo = __expf(-2.f * (dd * dd - dmin * dmin));   // <=1; lane r=ci has 1
            float Z = eo;
            Z += __shfl_xor(Z, 1, 32);
            Z += __shfl_xor(Z, 2, 32);
            Z += __shfl_xor(Z, 4, 32);
            Z += __shfl_xor(Z, 8, 32);
            Z += __shfl_xor(Z, 16, 32);
            float g = coef * eo / Z;
            const float4* xb = (const float4*)(xtab + sub * 2048 + rs * 64 + fgrp * 8);
            float xa[4], xc[4];
            *(float4*)xa = xb[0]; *(float4*)xc = xb[1];
            #pragma unroll
            for (int i = 0; i < 4; ++i) oreg[i] += g * (xa[i] - oreg[i]);
            #pragma unroll
            for (int i = 0; i < 4; ++i) oreg[4 + i] += g * (xc[i] - oreg[4 + i]);
            posn += coef;
        }
    }

    #pragma unroll
    for (int i = 0; i < 8; ++i) {
        ST<F32>(A.outp, b * 2048 + (fgrp * 8 + i) * 32 + my_r, oreg[i]);
    }
}

__global__ __launch_bounds__(256) void scan_kernel(Args A, const float* Y) {
    __shared__ ScanSmem S;
    __shared__ int dt_s;
    const int t = threadIdx.x, b = blockIdx.x;
    int isf32 = probe_is_f32<true>(A.ctx, t, &dt_s);
    if (isf32) scan_body<true>(S, t, b, A, Y);
    else       scan_body<false>(S, t, b, A, Y);
}

// ============================================================================
// Fallback: proven round-2 monolithic kernel (used only if ws too small)
// ============================================================================
struct Smem {
    float U[6144];
    float form_s[64 * 33];
    float match_s[512];
    float wch_s[1024];
    float vch_s[1024];
    float vep0_s[1024];
    float vep2_s[1024];
    float wep0_s[16], wep2_s[16], wdl_s[16];
    float wnc_s[64];
    float sc_s[2];
    float ssum_s[96];
};

template<bool F32>
__device__ void mono_body(Smem& S, int t, int b, const Args& A) {
    float* c_s  = S.U;
    float* modl = S.U + 128;
    float* Wk_s = S.U + 224;
    float* bk_s = S.U + 3344;
    float* xtab = S.U;

    if (t < 128) c_s[t] = LD<F32>(A.ctx, b * 128 + t);
    {
        int e0 = b * 2048 + t * 8;
        float4 x = LD4<F32>(A.form, e0);
        float4 y = LD4<F32>(A.form, e0 + 4);
        int f = t >> 2, r0 = (t & 3) * 8;
        float* dst = S.form_s + f * 33 + r0;
        dst[0] = x.x; dst[1] = x.y; dst[2] = x.z; dst[3] = x.w;
        dst[4] = y.x; dst[5] = y.y; dst[6] = y.z; dst[7] = y.w;
    }
    __syncthreads();

    if (t < 96) {
        float a = LD<F32>(A.mod_b, t);
        for (int cc = 0; cc < 128; ++cc) a += c_s[cc] * LD<F32>(A.mod_W, cc * 96 + t);
        modl[t] = a;
    }
    __syncthreads();
    if (t < 16) {
        float v[6]; float mx = -1e30f;
        #pragma unroll
        for (int j = 0; j < 6; ++j) { v[j] = modl[t * 6 + j]; mx = fmaxf(mx, v[j]); }
        float s = 0.f;
        #pragma unroll
        for (int j = 0; j < 6; ++j) { v[j] = __expf(v[j] - mx); s += v[j]; }
        float inv = 1.f / s;
        #pragma unroll
        for (int j = 0; j < 6; ++j) modl[t * 6 + j] = v[j] * inv;
    }
    __syncthreads();

    for (int j = t; j < 512; j += 256) {
        int n0 = j * 2;
        float2 bb = LD2<F32>(A.wch_b, n0);
        float a0 = bb.x, a1 = bb.y;
        for (int cc = 0; cc < 128; ++cc) {
            float2 w = LD2<F32>(A.wch_W, cc * 1024 + n0); float cv = c_s[cc];
            a0 += cv * w.x; a1 += cv * w.y;
        }
        int p = n0 >> 6; float sc = modl[p * 6 + 0];
        S.wch_s[n0] = sc * a0; S.wch_s[n0 + 1] = sc * a1;
    }
    for (int j = t; j < 512; j += 256) {
        int n0 = j * 2;
        float2 bb = LD2<F32>(A.vch_b, n0);
        float a0 = bb.x, a1 = bb.y;
        for (int cc = 0; cc < 128; ++cc) {
            float2 w = LD2<F32>(A.vch_W, cc * 1024 + n0); float cv = c_s[cc];
            a0 += cv * w.x; a1 += cv * w.y;
        }
        S.vch_s[n0] = a0; S.vch_s[n0 + 1] = a1;
    }
    for (int u = t; u < 1024; u += 256) {
        int n0 = u * 4;
        float4 bb = LD4<F32>(A.vep_b, n0);
        float a0 = bb.x, a2 = bb.z;
        for (int cc = 0; cc < 128; ++cc) {
            float4 w = LD4<F32>(A.vep_W, cc * 4096 + n0); float cv = c_s[cc];
            a0 += cv * w.x; a2 += cv * w.z;
        }
        S.vep0_s[u] = a0; S.vep2_s[u] = a2;
    }
    for (int j = t; j < 1536; j += 256) {
        int k  = j >> 9;
        int jj = j & 511;
        int n0 = jj * 2;
        float2 bb = LD2<F32>(A.m_Wb, k * 1024 + n0);
        float a0 = bb.x, a1 = bb.y;
        for (int cc = 0; cc < 128; ++cc) {
            float2 w = LD2<F32>(A.m_W, (k * 128 + cc) * 1024 + n0); float cv = c_s[cc];
            a0 += cv * w.x; a1 += cv * w.y;
        }
        int p = n0 >> 6, f = n0 & 63;
        Wk_s[(k * 16 + p) * 65 + f]     = a0;
        Wk_s[(k * 16 + p) * 65 + f + 1] = a1;
    }
    if (t < 16) {
        int n0 = t * 4;
        float4 bb = LD4<F32>(A.wep_b, n0);
        float a0 = bb.x, a2 = bb.z;
        for (int cc = 0; cc < 128; ++cc) {
            float4 w = LD4<F32>(A.wep_W, cc * 64 + n0); float cv = c_s[cc];
            a0 += cv * w.x; a2 += cv * w.z;
        }
        S.wep0_s[t] = modl[t * 6 + 2] * a0;
        S.wep2_s[t] = modl[t * 6 + 4] * a2;
    } else if (t < 32) {
        int p = t - 16;
        float a = LD<F32>(A.wdl_b, p);
        for (int cc = 0; cc < 128; ++cc) a += c_s[cc] * LD<F32>(A.wdl_W, cc * 16 + p);
        S.wdl_s[p] = modl[p * 6 + 1] * a;
    } else if (t < 96) {
        int f = t - 32;
        float a = LD<F32>(A.wnc_b, f);
        for (int cc = 0; cc < 128; ++cc) a += c_s[cc] * LD<F32>(A.wnc_W, cc * 64 + f);
        S.wnc_s[f] = __expf(a);
    } else if (t < 98) {
        const void* W  = (t == 96) ? A.wnd_W : A.wne_W;
        const void* bb = (t == 96) ? A.wnd_b : A.wne_b;
        float a = LD<F32>(bb, 0);
        for (int cc = 0; cc < 128; ++cc) a += c_s[cc] * LD<F32>(W, cc);
        S.sc_s[t - 96] = __expf(a);
    } else if (t < 146) {
        int i = t - 98;
        int k = i >> 4, p = i & 15;
        float a = LD<F32>(A.mb_b, k * 16 + p);
        for (int cc = 0; cc < 128; ++cc) a += c_s[cc] * LD<F32>(A.mb_W, (k * 128 + cc) * 16 + p);
        bk_s[i] = a;
    }
    __syncthreads();

    for (int idx = t; idx < 512; idx += 256) {
        int p = idx >> 5, r = idx & 31;
        float s0 = bk_s[p], s1 = bk_s[16 + p], s2 = bk_s[32 + p];
        const float* w0 = Wk_s + p * 65;
        const float* w1 = Wk_s + (16 + p) * 65;
        const float* w2 = Wk_s + (32 + p) * 65;
        for (int f = 0; f < 64; ++f) {
            const float* fr = S.form_s + f * 33 + r;
            float fm1 = (r > 0)  ? fr[-1] : 0.f;
            float f0  = fr[0];
            float fp1 = (r < 31) ? fr[1]  : 0.f;
            s0 += w0[f] * fm1; s1 += w1[f] * f0; s2 += w2[f] * fp1;
        }
        S.match_s[p * 32 + r] = __expf(lsg(s0) + lsg(s1) + lsg(s2));
    }
    __syncthreads();

    if (t < 96) {
        int which = t >> 5, r = t & 31;
        const float* w = (which == 0) ? S.wep0_s : (which == 1) ? S.wep2_s : S.wdl_s;
        float s = 0.f;
        for (int p = 0; p < 16; ++p) s += S.match_s[p * 32 + r] * w[p];
        S.ssum_s[which * 32 + r] = s;
    }
    #pragma unroll 1
    for (int q = 0; q < 24; ++q) {
        int idx = t + 256 * q;
        int sub = idx >> 11;
        int rs  = (idx >> 6) & 31;
        int f   = idx & 63;
        float x;
        if (sub == 1) {
            float sum = 0.f, vs = 0.f;
            for (int p = 0; p < 16; ++p) {
                float wc = S.match_s[p * 32 + rs] * S.wch_s[p * 64 + f];
                sum += wc;
                vs  += fmaxf(wc, 0.f) * S.vch_s[p * 64 + f];
            }
            float pch = sigm(sum - S.wnc_s[f]);
            float si  = S.form_s[f * 33 + rs];
            x = si + pch * (vs - si);
        } else {
            const float* wep = (sub == 0) ? S.wep0_s : S.wep2_s;
            const float* vep = (sub == 0) ? S.vep0_s : S.vep2_s;
            float vs = 0.f;
            for (int p = 0; p < 16; ++p) {
                float w = S.match_s[p * 32 + rs] * wep[p];
                vs += fmaxf(w, 0.f) * vep[p * 64 + f];
            }
            x = vs;
        }
        xtab[idx] = x;
    }
    __syncthreads();

    const int my_r = t & 31;
    const int fgrp = t >> 5;
    float oreg[8];
    #pragma unroll
    for (int i = 0; i < 8; ++i) oreg[i] = 0.f;
    float posn = 0.f;
    const float wnd1v = S.sc_s[0];
    const float wne1v = S.sc_s[1];

    for (int rs = 0; rs < 32; ++rs) {
        #pragma unroll
        for (int sub = 0; sub < 3; ++sub) {
            float coef;
            if (sub == 1) coef = 1.f - sigm(S.ssum_s[64 + rs] - wnd1v);
            else          coef = sigm(S.ssum_s[(sub & 2) * 16 + rs] - wne1v);
            float pc = fminf(posn, 31.f);
            int ci = (int)(pc + 0.5f);
            int lo = ci - 4; if (lo < 0)  lo = 0;
            int hi = ci + 4; if (hi > 31) hi = 31;
            float dmin = posn - (float)ci;
            float mx = -2.f * dmin * dmin;
            float Z = 0.f, eo = 0.f;
            for (int r = lo; r <= hi; ++r) {
                float d = posn - (float)r;
                float e = __expf(-2.f * d * d - mx);
                Z += e;
                if (r == my_r) eo = e;
            }
            float g = coef * eo / Z;
            const float* xb = xtab + (sub * 2048 + rs * 64 + fgrp * 8);
            #pragma unroll
            for (int i = 0; i < 8; ++i) oreg[i] += g * (xb[i] - oreg[i]);
            posn += coef;
        }
    }

    #pragma unroll
    for (int i = 0; i < 8; ++i) {
        ST<F32>(A.outp, b * 2048 + (fgrp * 8 + i) * 32 + my_r, oreg[i]);
    }
}

__global__ __launch_bounds__(256) void phon_mono(Args A) {
    __shared__ Smem S;
    __shared__ int dt_s;
    const int t = threadIdx.x, b = blockIdx.x;
    int isf32 = probe_is_f32<true>(A.ctx, t, &dt_s);
    if (isf32) mono_body<true>(S, t, b, A);
    else       mono_body<false>(S, t, b, A);
}

extern "C" void kernel_launch(void* const* d_in, const int* in_sizes, int n_in,
                              void* d_out, int out_size, void* d_ws, size_t ws_size,
                              hipStream_t stream) {
    Args A;
    A.form  = d_in[0];  A.ctx   = d_in[1];
    A.mod_W = d_in[2];  A.mod_b = d_in[3];
    A.wch_W = d_in[4];  A.wch_b = d_in[5];
    A.wdl_W = d_in[6];  A.wdl_b = d_in[7];
    A.wep_W = d_in[8];  A.wep_b = d_in[9];
    A.vch_W = d_in[10]; A.vch_b = d_in[11];
    A.vep_W = d_in[12]; A.vep_b = d_in[13];
    A.wnc_W = d_in[14]; A.wnc_b = d_in[15];
    A.wnd_W = d_in[16]; A.wnd_b = d_in[17];
    A.wne_W = d_in[18]; A.wne_b = d_in[19];
    A.m_W   = d_in[20]; A.m_Wb  = d_in[21];
    A.mb_W  = d_in[22]; A.mb_b  = d_in[23];
    A.outp  = d_out;

    const size_t need = (size_t)B_ * YSTRIDE * sizeof(float);
    if (ws_size >= need) {
        float* Y = (float*)d_ws;
        gemm_kernel<<<1024, 256, 0, stream>>>(A, Y);
        scan_kernel<<<B_, 256, 0, stream>>>(A, Y);
    } else {
        phon_mono<<<B_, 256, 0, stream>>>(A);
    }
}

// Round 4
// 311.465 us; speedup vs baseline: 3.0980x; 2.0216x over previous
//
#include <hip/hip_runtime.h>

// Problem constants: B=2048, F=64, R=32, P=16, C=128, TAU=2.0
#define B_ 2048
#define NTOT 7426
#define YSTRIDE 7432
#define WSTRIDE 8192

typedef unsigned short u16;
typedef unsigned int   u32;
typedef __attribute__((ext_vector_type(2))) float v2f;

__device__ __forceinline__ float bfu(u16 u) {
    u32 i = ((u32)u) << 16; float f; __builtin_memcpy(&f, &i, 4); return f;
}
__device__ __forceinline__ float bflo(u32 w) {
    u32 i = w << 16; float f; __builtin_memcpy(&f, &i, 4); return f;
}
__device__ __forceinline__ float bfhi(u32 w) {
    u32 i = w & 0xffff0000u; float f; __builtin_memcpy(&f, &i, 4); return f;
}
__device__ __forceinline__ u16 f2bf(float v) {
    u32 iv; __builtin_memcpy(&iv, &v, 4);
    u32 r = (iv + 0x7fffu + ((iv >> 16) & 1u)) >> 16;
    return (u16)r;
}
__device__ __forceinline__ float sigm(float x) { return 1.f / (1.f + __expf(-x)); }
__device__ __forceinline__ float lsg(float x) {
    return fminf(x, 0.f) - log1pf(__expf(-fabsf(x)));
}

template<bool F32> __device__ __forceinline__ float LD(const void* p, int e) {
    if (F32) return ((const float*)p)[e];
    return bfu(((const u16*)p)[e]);
}
template<bool F32> __device__ __forceinline__ float2 LD2(const void* p, int e) { // e even
    if (F32) { const float* q = (const float*)p; return make_float2(q[e], q[e + 1]); }
    u32 w = ((const u32*)p)[e >> 1];
    return make_float2(bflo(w), bfhi(w));
}
template<bool F32> __device__ __forceinline__ float4 LD4(const void* p, int e) { // e%4==0
    if (F32) return ((const float4*)p)[e >> 2];
    uint2 w = ((const uint2*)p)[e >> 2];
    return make_float4(bflo(w.x), bfhi(w.x), bflo(w.y), bfhi(w.y));
}
template<bool F32> __device__ __forceinline__ void ST(void* p, int e, float v) {
    if (F32) ((float*)p)[e] = v; else ((u16*)p)[e] = f2bf(v);
}

struct Args {
    const void *form, *ctx;
    const void *mod_W, *mod_b, *wch_W, *wch_b, *wdl_W, *wdl_b, *wep_W, *wep_b;
    const void *vch_W, *vch_b, *vep_W, *vep_b;
    const void *wnc_W, *wnc_b, *wnd_W, *wnd_b, *wne_W, *wne_b;
    const void *m_W, *m_Wb, *mb_W, *mb_b;
    void* outp;
};

// dtype probe: block-uniform, deterministic. Returns 1 if inputs are fp32.
__device__ __forceinline__ int probe_is_f32(const void* ctx, int t, int* flag_s) {
    if (t == 0) {
        int sane = 0;
        const u16* q = (const u16*)ctx;
        for (int i = 0; i < 64; ++i) {
            u16 u = q[2 * i];
            int ex = (u >> 7) & 0xFF;
            sane += (u == 0 || (ex >= 112 && ex <= 143)) ? 1 : 0;
        }
        *flag_s = (sane < 32) ? 1 : 0;
    }
    __syncthreads();
    return *flag_s;
}

// ============================================================================
// Column layout (NTOT=7426, padded to WSTRIDE=8192):
//  [0,96)    mod       [96,1120)  wch       [1120,2144) vch
//  [2144,4192) vepI (n=2144+2u+s -> vep col 4u+2s)
//  [4192,7264) Wk (k*1024 + p*64 + f)       [7264,7312) bk (k*16+p)
//  [7312,7344) wepI (n=7312+2u+s -> wep col 4u+2s)
//  [7344,7360) wdl   [7360,7424) wnc   [7424] wnd   [7425] wne  [7426,8192) 0
// ============================================================================

// ---------------- Kernel 0: repack weights -> Wcat[128][WSTRIDE], bcat ------
template<bool F32>
__device__ void repack_body(int idx, const Args& A, float* Wcat, float* bcat) {
    int n = idx & (WSTRIDE - 1);
    int c = idx >> 13;
    float w = 0.f, bb = 0.f;
    if (n < 96)        { w = LD<F32>(A.mod_W, c * 96 + n);   bb = LD<F32>(A.mod_b, n); }
    else if (n < 1120) { int j = n - 96;   w = LD<F32>(A.wch_W, c * 1024 + j); bb = LD<F32>(A.wch_b, j); }
    else if (n < 2144) { int j = n - 1120; w = LD<F32>(A.vch_W, c * 1024 + j); bb = LD<F32>(A.vch_b, j); }
    else if (n < 4192) { int i = n - 2144; int col = 4 * (i >> 1) + 2 * (i & 1);
                         w = LD<F32>(A.vep_W, c * 4096 + col); bb = LD<F32>(A.vep_b, col); }
    else if (n < 7264) { int i = n - 4192; int k = i >> 10, j = i & 1023;
                         w = LD<F32>(A.m_W, (k * 128 + c) * 1024 + j); bb = LD<F32>(A.m_Wb, k * 1024 + j); }
    else if (n < 7312) { int i = n - 7264; int k = i >> 4, p = i & 15;
                         w = LD<F32>(A.mb_W, (k * 128 + c) * 16 + p); bb = LD<F32>(A.mb_b, k * 16 + p); }
    else if (n < 7344) { int i = n - 7312; int col = 4 * (i >> 1) + 2 * (i & 1);
                         w = LD<F32>(A.wep_W, c * 64 + col); bb = LD<F32>(A.wep_b, col); }
    else if (n < 7360) { int j = n - 7344; w = LD<F32>(A.wdl_W, c * 16 + j); bb = LD<F32>(A.wdl_b, j); }
    else if (n < 7424) { int j = n - 7360; w = LD<F32>(A.wnc_W, c * 64 + j); bb = LD<F32>(A.wnc_b, j); }
    else if (n == 7424){ w = LD<F32>(A.wnd_W, c); bb = LD<F32>(A.wnd_b, 0); }
    else if (n == 7425){ w = LD<F32>(A.wne_W, c); bb = LD<F32>(A.wne_b, 0); }
    Wcat[idx] = w;
    if (c == 0) bcat[n] = bb;
}

__global__ __launch_bounds__(256) void repack_kernel(Args A, float* Wcat, float* bcat) {
    __shared__ int dt_s;
    const int t = threadIdx.x;
    int isf32 = probe_is_f32(A.ctx, t, &dt_s);
    int idx = blockIdx.x * 256 + t;
    if (isf32) repack_body<true>(idx, A, Wcat, bcat);
    else       repack_body<false>(idx, A, Wcat, bcat);
}

// ---------------- Kernel 1: uniform GEMM  Y = ctx @ Wcat + bcat -------------
// block: 16 rows x 1024 cols; thread: 16 rows x 4 cols (v2f acc -> pk_fma)
template<bool F32>
__device__ void gemm2_body(float (*ctx_s)[128], int t, int blk, const void* ctx,
                           const float* __restrict__ Wcat, const float* __restrict__ bcat,
                           float* __restrict__ Y) {
    const int cb = blk & 7;
    const int mb = (blk >> 3) * 16;

    for (int i = t; i < 512; i += 256) {
        int m = i >> 5, c0 = (i & 31) * 4;
        float4 v = LD4<F32>(ctx, (mb + m) * 128 + c0);
        *(float4*)&ctx_s[m][c0] = v;
    }
    __syncthreads();

    const int n0 = cb * 1024 + 4 * t;
    const float4* W4 = (const float4*)Wcat;       // [c][WSTRIDE/4]
    const int wcol = n0 >> 2;

    float4 bv = *(const float4*)(bcat + n0);
    v2f acc[16][2];
    #pragma unroll
    for (int m = 0; m < 16; ++m) {
        acc[m][0].x = bv.x; acc[m][0].y = bv.y;
        acc[m][1].x = bv.z; acc[m][1].y = bv.w;
    }

    float4 w[4];
    #pragma unroll
    for (int j = 0; j < 4; ++j) w[j] = W4[(size_t)j * 2048 + wcol];

    #pragma unroll 1
    for (int c4 = 0; c4 < 128; c4 += 4) {
        float4 wn[4];
        if (c4 + 4 < 128) {
            #pragma unroll
            for (int j = 0; j < 4; ++j) wn[j] = W4[(size_t)(c4 + 4 + j) * 2048 + wcol];
        }
        #pragma unroll
        for (int m = 0; m < 16; ++m) {
            float4 cv = *(const float4*)&ctx_s[m][c4];
            float cs[4] = {cv.x, cv.y, cv.z, cv.w};
            #pragma unroll
            for (int j = 0; j < 4; ++j) {
                v2f cc; cc.x = cs[j]; cc.y = cs[j];
                v2f w01; w01.x = w[j].x; w01.y = w[j].y;
                v2f w23; w23.x = w[j].z; w23.y = w[j].w;
                acc[m][0] += cc * w01;
                acc[m][1] += cc * w23;
            }
        }
        #pragma unroll
        for (int j = 0; j < 4; ++j) w[j] = wn[j];
    }

    if (n0 < YSTRIDE) {
        #pragma unroll
        for (int m = 0; m < 16; ++m) {
            float4 s;
            s.x = acc[m][0].x; s.y = acc[m][0].y; s.z = acc[m][1].x; s.w = acc[m][1].y;
            *(float4*)(Y + (size_t)(mb + m) * YSTRIDE + n0) = s;
        }
    }
}

__global__ __launch_bounds__(256) void gemm2_kernel(Args A, const float* Wcat,
                                                    const float* bcat, float* Y) {
    __shared__ float ctx_s[16][128];
    __shared__ int dt_s;
    const int t = threadIdx.x, blk = blockIdx.x;
    int isf32 = probe_is_f32(A.ctx, t, &dt_s);
    if (isf32) gemm2_body<true>(ctx_s, t, blk, A.ctx, Wcat, bcat, Y);
    else       gemm2_body<false>(ctx_s, t, blk, A.ctx, Wcat, bcat, Y);
}

// ---------------- Mid-tier GEMM (round-3, branchy; used only if ws tight) ---
struct PD { const void* p0; int off; int st; int mode; float b0, b1; };

template<bool F32>
__device__ __forceinline__ void resolve(const Args& A, int n0, PD& d) {
    if (n0 < 96) {
        d.mode = 0; d.p0 = A.mod_W; d.off = n0; d.st = 96;
        float2 b = LD2<F32>(A.mod_b, n0); d.b0 = b.x; d.b1 = b.y;
    } else if (n0 < 1120) {
        int j = n0 - 96;
        d.mode = 0; d.p0 = A.wch_W; d.off = j; d.st = 1024;
        float2 b = LD2<F32>(A.wch_b, j); d.b0 = b.x; d.b1 = b.y;
    } else if (n0 < 2144) {
        int j = n0 - 1120;
        d.mode = 0; d.p0 = A.vch_W; d.off = j; d.st = 1024;
        float2 b = LD2<F32>(A.vch_b, j); d.b0 = b.x; d.b1 = b.y;
    } else if (n0 < 4192) {
        int u = (n0 - 2144) >> 1;
        d.mode = 1; d.p0 = A.vep_W; d.off = 4 * u; d.st = 4096;
        float4 b = LD4<F32>(A.vep_b, 4 * u); d.b0 = b.x; d.b1 = b.z;
    } else if (n0 < 7264) {
        int i = n0 - 4192; int k = i >> 10, j = i & 1023;
        d.mode = 0; d.p0 = A.m_W; d.off = k * 131072 + j; d.st = 1024;
        float2 b = LD2<F32>(A.m_Wb, k * 1024 + j); d.b0 = b.x; d.b1 = b.y;
    } else if (n0 < 7312) {
        int i = n0 - 7264; int k = i >> 4, p = i & 15;
        d.mode = 0; d.p0 = A.mb_W; d.off = k * 2048 + p; d.st = 16;
        float2 b = LD2<F32>(A.mb_b, k * 16 + p); d.b0 = b.x; d.b1 = b.y;
    } else if (n0 < 7344) {
        int u = (n0 - 7312) >> 1;
        d.mode = 1; d.p0 = A.wep_W; d.off = 4 * u; d.st = 64;
        float4 b = LD4<F32>(A.wep_b, 4 * u); d.b0 = b.x; d.b1 = b.z;
    } else if (n0 < 7360) {
        int j = n0 - 7344;
        d.mode = 0; d.p0 = A.wdl_W; d.off = j; d.st = 16;
        float2 b = LD2<F32>(A.wdl_b, j); d.b0 = b.x; d.b1 = b.y;
    } else if (n0 < 7424) {
        int j = n0 - 7360;
        d.mode = 0; d.p0 = A.wnc_W; d.off = j; d.st = 64;
        float2 b = LD2<F32>(A.wnc_b, j); d.b0 = b.x; d.b1 = b.y;
    } else if (n0 == 7424) {
        d.mode = 2; d.p0 = A.wnd_W; d.off = 0; d.st = 1;
        d.b0 = LD<F32>(A.wnd_b, 0); d.b1 = LD<F32>(A.wne_b, 0);
    } else {
        d.mode = 3; d.p0 = A.mod_W; d.off = 0; d.st = 0; d.b0 = 0.f; d.b1 = 0.f;
    }
}

template<bool F32>
__device__ __forceinline__ v2f fetchw(const PD& d, const Args& A, int c) {
    if (d.mode == 0) {
        float2 w = LD2<F32>(d.p0, d.off + c * d.st);
        v2f r; r.x = w.x; r.y = w.y; return r;
    } else if (d.mode == 1) {
        float4 q = LD4<F32>(d.p0, d.off + c * d.st);
        v2f r; r.x = q.x; r.y = q.z; return r;
    } else if (d.mode == 2) {
        v2f r; r.x = LD<F32>(A.wnd_W, c); r.y = LD<F32>(A.wne_W, c); return r;
    }
    v2f r; r.x = 0.f; r.y = 0.f; return r;
}

template<bool F32>
__device__ void gemm_body(float (*ctx_s)[128], int t, int blk, const Args& A, float* Y) {
    const int cb = blk & 3;
    const int mb = (blk >> 2) * 8;
    {
        int m = t >> 5, c0 = (t & 31) * 4;
        float4 v = LD4<F32>(A.ctx, (mb + m) * 128 + c0);
        ctx_s[m][c0] = v.x; ctx_s[m][c0 + 1] = v.y; ctx_s[m][c0 + 2] = v.z; ctx_s[m][c0 + 3] = v.w;
    }
    __syncthreads();
    PD d[4]; int n0[4];
    #pragma unroll
    for (int i = 0; i < 4; ++i) { n0[i] = cb * 2048 + i * 512 + 2 * t; resolve<F32>(A, n0[i], d[i]); }
    v2f acc[4][8];
    #pragma unroll
    for (int i = 0; i < 4; ++i)
        #pragma unroll
        for (int m = 0; m < 8; ++m) { acc[i][m].x = d[i].b0; acc[i][m].y = d[i].b1; }
    for (int c4 = 0; c4 < 32; ++c4) {
        float cv[8][4];
        #pragma unroll
        for (int m = 0; m < 8; ++m) *(float4*)cv[m] = *(const float4*)&ctx_s[m][c4 * 4];
        #pragma unroll
        for (int j = 0; j < 4; ++j) {
            int c = c4 * 4 + j;
            v2f w[4];
            #pragma unroll
            for (int i = 0; i < 4; ++i) w[i] = fetchw<F32>(d[i], A, c);
            #pragma unroll
            for (int m = 0; m < 8; ++m) {
                v2f cvv; cvv.x = cv[m][j]; cvv.y = cv[m][j];
                #pragma unroll
                for (int i = 0; i < 4; ++i) acc[i][m] += cvv * w[i];
            }
        }
    }
    #pragma unroll
    for (int i = 0; i < 4; ++i) {
        if (d[i].mode < 3) {
            #pragma unroll
            for (int m = 0; m < 8; ++m) {
                float2 s; s.x = acc[i][m].x; s.y = acc[i][m].y;
                *(float2*)(Y + (size_t)(mb + m) * YSTRIDE + n0[i]) = s;
            }
        }
    }
}

__global__ __launch_bounds__(256) void gemm_kernel(Args A, float* Y) {
    __shared__ float ctx_s[8][128];
    __shared__ int dt_s;
    const int t = threadIdx.x, blk = blockIdx.x;
    int isf32 = probe_is_f32(A.ctx, t, &dt_s);
    if (isf32) gemm_body<true>(ctx_s, t, blk, A, Y);
    else       gemm_body<false>(ctx_s, t, blk, A, Y);
}

// ---------------- Kernel 2: match + xtab + parallel-gated scan --------------
struct __align__(16) ScanSmem {
    float U[6144];          // phases B-C: Wk(3072,p64) bk(48) modl(96); C2+: xtab
    float form_s[64 * 33];  // [f][r] pitch 33
    float match_s[512];     // [p][r]; phase D: ck_s(96)@0, pos_s(96)@128
    float wcv[4096];        // wch(1024) vch(1024) vepI(2048); D: gtab@+1024 (3072)
    float wnc_s[64];
    float wep0_s[16], wep2_s[16], wdl_s[16];
    float coef_s[96];       // [sub][rs]  (sub 0:ep0, 1:deln, 2:ep2)
    float sc_s[2];          // {w_nodeln, w_noepen}
};

template<bool F32>
__device__ void scan_body(ScanSmem& S, int t, int b, const Args& A, const float* __restrict__ Y) {
    float* Wk_s = S.U;
    float* bk_s = S.U + 3072;
    float* modl = S.U + 3120;
    float* xtab = S.U;            // overlay after phase C
    float* wch_s = S.wcv;
    float* vch_s = S.wcv + 1024;
    float* vepI_s = S.wcv + 2048;

    const float* Yr = Y + (size_t)b * YSTRIDE;
    const float4* Y4 = (const float4*)Yr;

    // ---- stage form + Y segments ----
    {
        int e0 = b * 2048 + t * 8;
        float4 x = LD4<F32>(A.form, e0);
        float4 y = LD4<F32>(A.form, e0 + 4);
        int f = t >> 2, r0 = (t & 3) * 8;
        float* dst = S.form_s + f * 33 + r0;
        dst[0] = x.x; dst[1] = x.y; dst[2] = x.z; dst[3] = x.w;
        dst[4] = y.x; dst[5] = y.y; dst[6] = y.z; dst[7] = y.w;
    }
    for (int i = t; i < 768; i += 256) ((float4*)Wk_s)[i] = Y4[1048 + i];    // Wk @4192
    if (t < 12) ((float4*)bk_s)[t] = Y4[1816 + t];                           // bk @7264
    if (t < 24) ((float4*)modl)[t] = Y4[t];                                  // mod @0
    ((float4*)wch_s)[t] = Y4[24 + t];                                        // wch @96
    ((float4*)vch_s)[t] = Y4[280 + t];                                       // vch @1120
    for (int i = t; i < 512; i += 256) ((float4*)vepI_s)[i] = Y4[536 + i];   // vepI @2144
    if (t < 16) {
        S.wep0_s[t] = Yr[7312 + 2 * t];
        S.wep2_s[t] = Yr[7312 + 2 * t + 1];
        S.wdl_s[t]  = Yr[7344 + t];
    } else if (t >= 32 && t < 96) {
        S.wnc_s[t - 32] = __expf(Yr[7360 + (t - 32)]);
    } else if (t >= 96 && t < 98) {
        S.sc_s[t - 96] = __expf(Yr[7424 + (t - 96)]);
    }
    __syncthreads();

    // ---- softmax(6) on mod ----
    if (t < 16) {
        float v[6]; float mx = -1e30f;
        #pragma unroll
        for (int j = 0; j < 6; ++j) { v[j] = modl[t * 6 + j]; mx = fmaxf(mx, v[j]); }
        float s = 0.f;
        #pragma unroll
        for (int j = 0; j < 6; ++j) { v[j] = __expf(v[j] - mx); s += v[j]; }
        float inv = 1.f / s;
        #pragma unroll
        for (int j = 0; j < 6; ++j) modl[t * 6 + j] = v[j] * inv;
    }
    __syncthreads();

    // ---- mod scaling + phase C (match) ----
    if (t < 16) {
        S.wep0_s[t] *= modl[t * 6 + 2];
        S.wep2_s[t] *= modl[t * 6 + 4];
        S.wdl_s[t]  *= modl[t * 6 + 1];
    }
    for (int i = t; i < 1024; i += 256) wch_s[i] *= modl[(i >> 6) * 6];

    const int my_r = t & 31;
    #pragma unroll 1
    for (int it = 0; it < 2; ++it) {
        int idx = t + 256 * it;
        int p = idx >> 5, r = idx & 31;
        float s0 = bk_s[p], s1 = bk_s[16 + p], s2 = bk_s[32 + p];
        const float4* w0 = (const float4*)(Wk_s + p * 64);
        const float4* w1 = (const float4*)(Wk_s + (16 + p) * 64);
        const float4* w2 = (const float4*)(Wk_s + (32 + p) * 64);
        for (int f4 = 0; f4 < 16; ++f4) {
            float a0[4], a1[4], a2[4];
            *(float4*)a0 = w0[f4]; *(float4*)a1 = w1[f4]; *(float4*)a2 = w2[f4];
            #pragma unroll
            for (int j = 0; j < 4; ++j) {
                int f = f4 * 4 + j;
                float f0 = S.form_s[f * 33 + r];
                float fm = __shfl_up(f0, 1, 32);   if (r == 0)  fm = 0.f;
                float fp = __shfl_down(f0, 1, 32); if (r == 31) fp = 0.f;
                s0 += a0[j] * fm; s1 += a1[j] * f0; s2 += a2[j] * fp;
            }
        }
        S.match_s[p * 32 + r] = __expf(lsg(s0) + lsg(s1) + lsg(s2));
    }
    __syncthreads();

    // ---- phase C2: coef + xtab (xtab overlays U) ----
    if (t < 96) {
        int sub = t >> 5, r = t & 31;
        const float* w = (sub == 0) ? S.wep0_s : (sub == 1) ? S.wdl_s : S.wep2_s;
        float s = 0.f;
        for (int p = 0; p < 16; ++p) s += S.match_s[p * 32 + r] * w[p];
        float cf;
        if (sub == 1) cf = 1.f - sigm(s - S.sc_s[0]);   // 1 - p_deln
        else          cf = sigm(s - S.sc_s[1]);         // p_epen
        S.coef_s[sub * 32 + r] = cf;
    }
    #pragma unroll 1
    for (int q = 0; q < 24; ++q) {
        int idx = t + 256 * q;                     // idx = sub*2048 + rs*64 + f
        int sub = idx >> 11;
        int rs  = (idx >> 6) & 31;
        int f   = idx & 63;
        float x;
        if (sub == 1) {
            float sum = 0.f, vs = 0.f;
            for (int p = 0; p < 16; ++p) {
                float wc = S.match_s[p * 32 + rs] * wch_s[p * 64 + f];
                sum += wc;
                vs  += fmaxf(wc, 0.f) * vch_s[p * 64 + f];
            }
            float pch = sigm(sum - S.wnc_s[f]);
            float si  = S.form_s[f * 33 + rs];
            x = si + pch * (vs - si);              // sym
        } else {
            const float* wep = (sub == 0) ? S.wep0_s : S.wep2_s;
            int s1i = (sub == 0) ? 0 : 1;
            float vs = 0.f;
            for (int p = 0; p < 16; ++p) {
                float w = S.match_s[p * 32 + rs] * wep[p];
                vs += fmaxf(w, 0.f) * vepI_s[2 * (p * 64 + f) + s1i];
            }
            x = vs;
        }
        xtab[idx] = x;
    }
    __syncthreads();

    // ---- phase D-prep: k-ordered coefs (k = rs*3+sub) + exclusive prefix ----
    float* ck_s  = S.match_s;        // match dead after xtab
    float* pos_s = S.match_s + 128;
    float* gtab  = S.wcv + 1024;     // 3072 floats; vch+vepI dead after xtab
    if (t < 96) ck_s[t] = S.coef_s[(t % 3) * 32 + (t / 3)];
    __syncthreads();
    if (t < 64) {
        float a = ck_s[t];
        float a0 = a;
        #pragma unroll
        for (int d = 1; d < 64; d <<= 1) { float v = __shfl_up(a, d, 64); if (t >= d) a += v; }
        pos_s[t] = a - a0;                          // exclusive prefix
        float carry = __shfl(a, 63, 64);            // inclusive sum of first 64
        float b2 = (t < 32) ? ck_s[64 + t] : 0.f;
        float c2 = b2;
        #pragma unroll
        for (int d = 1; d < 32; d <<= 1) { float v = __shfl_up(c2, d, 32); if ((t & 31) >= d) c2 += v; }
        if (t < 32) pos_s[64 + t] = carry + c2 - b2;
    }
    __syncthreads();

    // ---- gtab[k][r]: all 96 softmax-gates in parallel ----
    #pragma unroll 1
    for (int i = 0; i < 12; ++i) {
        int idx = t + 256 * i;                      // k = idx>>5 (wave-uniform/32), r = idx&31
        int k = idx >> 5, r = idx & 31;
        float posn = pos_s[k];
        float pc = fminf(posn, 31.f);
        float ci = floorf(pc + 0.5f);
        float dmin = posn - ci;
        float dd = posn - (float)r;
        float eo = __expf(-2.f * (dd * dd - dmin * dmin));   // exact, max-subtracted
        float Z = eo;
        Z += __shfl_xor(Z, 1, 32);
        Z += __shfl_xor(Z, 2, 32);
        Z += __shfl_xor(Z, 4, 32);
        Z += __shfl_xor(Z, 8, 32);
        Z += __shfl_xor(Z, 16, 32);
        gtab[idx] = ck_s[k] * eo / Z;
    }
    __syncthreads();

    // ---- phase D: pure-throughput blend, no serial transcendentals ----
    const int fgrp = t >> 5;
    v2f o01, o23, o45, o67;
    o01 = 0.f; o23 = 0.f; o45 = 0.f; o67 = 0.f;
    #pragma unroll 1
    for (int rs = 0; rs < 32; ++rs) {
        #pragma unroll
        for (int sub = 0; sub < 3; ++sub) {
            float g = gtab[(rs * 3 + sub) * 32 + my_r];
            v2f gv; gv.x = g; gv.y = g;
            const float4* xb = (const float4*)(xtab + sub * 2048 + rs * 64 + fgrp * 8);
            float4 xa = xb[0], xc = xb[1];
            v2f x01, x23, x45, x67;
            x01.x = xa.x; x01.y = xa.y; x23.x = xa.z; x23.y = xa.w;
            x45.x = xc.x; x45.y = xc.y; x67.x = xc.z; x67.y = xc.w;
            o01 += gv * (x01 - o01);
            o23 += gv * (x23 - o23);
            o45 += gv * (x45 - o45);
            o67 += gv * (x67 - o67);
        }
    }

    float oreg[8] = {o01.x, o01.y, o23.x, o23.y, o45.x, o45.y, o67.x, o67.y};
    #pragma unroll
    for (int i = 0; i < 8; ++i) {
        ST<F32>(A.outp, b * 2048 + (fgrp * 8 + i) * 32 + my_r, oreg[i]);
    }
}

__global__ __launch_bounds__(256) void scan_kernel(Args A, const float* Y) {
    __shared__ ScanSmem S;
    __shared__ int dt_s;
    const int t = threadIdx.x, b = blockIdx.x;
    int isf32 = probe_is_f32(A.ctx, t, &dt_s);
    if (isf32) scan_body<true>(S, t, b, A, Y);
    else       scan_body<false>(S, t, b, A, Y);
}

// ---------------- Last-resort monolithic fallback (round-2, proven) ---------
struct Smem {
    float U[6144];
    float form_s[64 * 33];
    float match_s[512];
    float wch_s[1024];
    float vch_s[1024];
    float vep0_s[1024];
    float vep2_s[1024];
    float wep0_s[16], wep2_s[16], wdl_s[16];
    float wnc_s[64];
    float sc_s[2];
    float ssum_s[96];
};

template<bool F32>
__device__ void mono_body(Smem& S, int t, int b, const Args& A) {
    float* c_s  = S.U;
    float* modl = S.U + 128;
    float* Wk_s = S.U + 224;
    float* bk_s = S.U + 3344;
    float* xtab = S.U;

    if (t < 128) c_s[t] = LD<F32>(A.ctx, b * 128 + t);
    {
        int e0 = b * 2048 + t * 8;
        float4 x = LD4<F32>(A.form, e0);
        float4 y = LD4<F32>(A.form, e0 + 4);
        int f = t >> 2, r0 = (t & 3) * 8;
        float* dst = S.form_s + f * 33 + r0;
        dst[0] = x.x; dst[1] = x.y; dst[2] = x.z; dst[3] = x.w;
        dst[4] = y.x; dst[5] = y.y; dst[6] = y.z; dst[7] = y.w;
    }
    __syncthreads();
    if (t < 96) {
        float a = LD<F32>(A.mod_b, t);
        for (int cc = 0; cc < 128; ++cc) a += c_s[cc] * LD<F32>(A.mod_W, cc * 96 + t);
        modl[t] = a;
    }
    __syncthreads();
    if (t < 16) {
        float v[6]; float mx = -1e30f;
        #pragma unroll
        for (int j = 0; j < 6; ++j) { v[j] = modl[t * 6 + j]; mx = fmaxf(mx, v[j]); }
        float s = 0.f;
        #pragma unroll
        for (int j = 0; j < 6; ++j) { v[j] = __expf(v[j] - mx); s += v[j]; }
        float inv = 1.f / s;
        #pragma unroll
        for (int j = 0; j < 6; ++j) modl[t * 6 + j] = v[j] * inv;
    }
    __syncthreads();
    for (int j = t; j < 512; j += 256) {
        int n0 = j * 2;
        float2 bb = LD2<F32>(A.wch_b, n0);
        float a0 = bb.x, a1 = bb.y;
        for (int cc = 0; cc < 128; ++cc) {
            float2 w = LD2<F32>(A.wch_W, cc * 1024 + n0); float cv = c_s[cc];
            a0 += cv * w.x; a1 += cv * w.y;
        }
        int p = n0 >> 6; float sc = modl[p * 6 + 0];
        S.wch_s[n0] = sc * a0; S.wch_s[n0 + 1] = sc * a1;
    }
    for (int j = t; j < 512; j += 256) {
        int n0 = j * 2;
        float2 bb = LD2<F32>(A.vch_b, n0);
        float a0 = bb.x, a1 = bb.y;
        for (int cc = 0; cc < 128; ++cc) {
            float2 w = LD2<F32>(A.vch_W, cc * 1024 + n0); float cv = c_s[cc];
            a0 += cv * w.x; a1 += cv * w.y;
        }
        S.vch_s[n0] = a0; S.vch_s[n0 + 1] = a1;
    }
    for (int u = t; u < 1024; u += 256) {
        int n0 = u * 4;
        float4 bb = LD4<F32>(A.vep_b, n0);
        float a0 = bb.x, a2 = bb.z;
        for (int cc = 0; cc < 128; ++cc) {
            float4 w = LD4<F32>(A.vep_W, cc * 4096 + n0); float cv = c_s[cc];
            a0 += cv * w.x; a2 += cv * w.z;
        }
        S.vep0_s[u] = a0; S.vep2_s[u] = a2;
    }
    for (int j = t; j < 1536; j += 256) {
        int k  = j >> 9;
        int jj = j & 511;
        int n0 = jj * 2;
        float2 bb = LD2<F32>(A.m_Wb, k * 1024 + n0);
        float a0 = bb.x, a1 = bb.y;
        for (int cc = 0; cc < 128; ++cc) {
            float2 w = LD2<F32>(A.m_W, (k * 128 + cc) * 1024 + n0); float cv = c_s[cc];
            a0 += cv * w.x; a1 += cv * w.y;
        }
        int p = n0 >> 6, f = n0 & 63;
        Wk_s[(k * 16 + p) * 65 + f]     = a0;
        Wk_s[(k * 16 + p) * 65 + f + 1] = a1;
    }
    if (t < 16) {
        int n0 = t * 4;
        float4 bb = LD4<F32>(A.wep_b, n0);
        float a0 = bb.x, a2 = bb.z;
        for (int cc = 0; cc < 128; ++cc) {
            float4 w = LD4<F32>(A.wep_W, cc * 64 + n0); float cv = c_s[cc];
            a0 += cv * w.x; a2 += cv * w.z;
        }
        S.wep0_s[t] = modl[t * 6 + 2] * a0;
        S.wep2_s[t] = modl[t * 6 + 4] * a2;
    } else if (t < 32) {
        int p = t - 16;
        float a = LD<F32>(A.wdl_b, p);
        for (int cc = 0; cc < 128; ++cc) a += c_s[cc] * LD<F32>(A.wdl_W, cc * 16 + p);
        S.wdl_s[p] = modl[p * 6 + 1] * a;
    } else if (t < 96) {
        int f = t - 32;
        float a = LD<F32>(A.wnc_b, f);
        for (int cc = 0; cc < 128; ++cc) a += c_s[cc] * LD<F32>(A.wnc_W, cc * 64 + f);
        S.wnc_s[f] = __expf(a);
    } else if (t < 98) {
        const void* W  = (t == 96) ? A.wnd_W : A.wne_W;
        const void* bb = (t == 96) ? A.wnd_b : A.wne_b;
        float a = LD<F32>(bb, 0);
        for (int cc = 0; cc < 128; ++cc) a += c_s[cc] * LD<F32>(W, cc);
        S.sc_s[t - 96] = __expf(a);
    } else if (t < 146) {
        int i = t - 98;
        int k = i >> 4, p = i & 15;
        float a = LD<F32>(A.mb_b, k * 16 + p);
        for (int cc = 0; cc < 128; ++cc) a += c_s[cc] * LD<F32>(A.mb_W, (k * 128 + cc) * 16 + p);
        bk_s[i] = a;
    }
    __syncthreads();
    for (int idx = t; idx < 512; idx += 256) {
        int p = idx >> 5, r = idx & 31;
        float s0 = bk_s[p], s1 = bk_s[16 + p], s2 = bk_s[32 + p];
        const float* w0 = Wk_s + p * 65;
        const float* w1 = Wk_s + (16 + p) * 65;
        const float* w2 = Wk_s + (32 + p) * 65;
        for (int f = 0; f < 64; ++f) {
            const float* fr = S.form_s + f * 33 + r;
            float fm1 = (r > 0)  ? fr[-1] : 0.f;
            float f0  = fr[0];
            float fp1 = (r < 31) ? fr[1]  : 0.f;
            s0 += w0[f] * fm1; s1 += w1[f] * f0; s2 += w2[f] * fp1;
        }
        S.match_s[p * 32 + r] = __expf(lsg(s0) + lsg(s1) + lsg(s2));
    }
    __syncthreads();
    if (t < 96) {
        int which = t >> 5, r = t & 31;
        const float* w = (which == 0) ? S.wep0_s : (which == 1) ? S.wep2_s : S.wdl_s;
        float s = 0.f;
        for (int p = 0; p < 16; ++p) s += S.match_s[p * 32 + r] * w[p];
        S.ssum_s[which * 32 + r] = s;
    }
    #pragma unroll 1
    for (int q = 0; q < 24; ++q) {
        int idx = t + 256 * q;
        int sub = idx >> 11;
        int rs  = (idx >> 6) & 31;
        int f   = idx & 63;
        float x;
        if (sub == 1) {
            float sum = 0.f, vs = 0.f;
            for (int p = 0; p < 16; ++p) {
                float wc = S.match_s[p * 32 + rs] * S.wch_s[p * 64 + f];
                sum += wc;
                vs  += fmaxf(wc, 0.f) * S.vch_s[p * 64 + f];
            }
            float pch = sigm(sum - S.wnc_s[f]);
            float si  = S.form_s[f * 33 + rs];
            x = si + pch * (vs - si);
        } else {
            const float* wep = (sub == 0) ? S.wep0_s : S.wep2_s;
            const float* vep = (sub == 0) ? S.vep0_s : S.vep2_s;
            float vs = 0.f;
            for (int p = 0; p < 16; ++p) {
                float w = S.match_s[p * 32 + rs] * wep[p];
                vs += fmaxf(w, 0.f) * vep[p * 64 + f];
            }
            x = vs;
        }
        xtab[idx] = x;
    }
    __syncthreads();
    const int my_r = t & 31;
    const int fgrp = t >> 5;
    float oreg[8];
    #pragma unroll
    for (int i = 0; i < 8; ++i) oreg[i] = 0.f;
    float posn = 0.f;
    const float wnd1v = S.sc_s[0];
    const float wne1v = S.sc_s[1];
    for (int rs = 0; rs < 32; ++rs) {
        #pragma unroll
        for (int sub = 0; sub < 3; ++sub) {
            float coef;
            if (sub == 1) coef = 1.f - sigm(S.ssum_s[64 + rs] - wnd1v);
            else          coef = sigm(S.ssum_s[(sub & 2) * 16 + rs] - wne1v);
            float pc = fminf(posn, 31.f);
            int ci = (int)(pc + 0.5f);
            int lo = ci - 4; if (lo < 0)  lo = 0;
            int hi = ci + 4; if (hi > 31) hi = 31;
            float dmin = posn - (float)ci;
            float mx = -2.f * dmin * dmin;
            float Z = 0.f, eo = 0.f;
            for (int r = lo; r <= hi; ++r) {
                float d = posn - (float)r;
                float e = __expf(-2.f * d * d - mx);
                Z += e;
                if (r == my_r) eo = e;
            }
            float g = coef * eo / Z;
            const float* xb = xtab + (sub * 2048 + rs * 64 + fgrp * 8);
            #pragma unroll
            for (int i = 0; i < 8; ++i) oreg[i] += g * (xb[i] - oreg[i]);
            posn += coef;
        }
    }
    #pragma unroll
    for (int i = 0; i < 8; ++i) {
        ST<F32>(A.outp, b * 2048 + (fgrp * 8 + i) * 32 + my_r, oreg[i]);
    }
}

__global__ __launch_bounds__(256) void phon_mono(Args A) {
    __shared__ Smem S;
    __shared__ int dt_s;
    const int t = threadIdx.x, b = blockIdx.x;
    int isf32 = probe_is_f32(A.ctx, t, &dt_s);
    if (isf32) mono_body<true>(S, t, b, A);
    else       mono_body<false>(S, t, b, A);
}

extern "C" void kernel_launch(void* const* d_in, const int* in_sizes, int n_in,
                              void* d_out, int out_size, void* d_ws, size_t ws_size,
                              hipStream_t stream) {
    Args A;
    A.form  = d_in[0];  A.ctx   = d_in[1];
    A.mod_W = d_in[2];  A.mod_b = d_in[3];
    A.wch_W = d_in[4];  A.wch_b = d_in[5];
    A.wdl_W = d_in[6];  A.wdl_b = d_in[7];
    A.wep_W = d_in[8];  A.wep_b = d_in[9];
    A.vch_W = d_in[10]; A.vch_b = d_in[11];
    A.vep_W = d_in[12]; A.vep_b = d_in[13];
    A.wnc_W = d_in[14]; A.wnc_b = d_in[15];
    A.wnd_W = d_in[16]; A.wnd_b = d_in[17];
    A.wne_W = d_in[18]; A.wne_b = d_in[19];
    A.m_W   = d_in[20]; A.m_Wb  = d_in[21];
    A.mb_W  = d_in[22]; A.mb_b  = d_in[23];
    A.outp  = d_out;

    const size_t needY = (size_t)B_ * YSTRIDE * sizeof(float);
    const size_t needW = needY + ((size_t)128 * WSTRIDE + WSTRIDE) * sizeof(float);
    if (ws_size >= needW) {
        float* Y    = (float*)d_ws;
        float* Wcat = Y + (size_t)B_ * YSTRIDE;
        float* bcat = Wcat + (size_t)128 * WSTRIDE;
        repack_kernel<<<(128 * WSTRIDE) / 256, 256, 0, stream>>>(A, Wcat, bcat);
        gemm2_kernel<<<1024, 256, 0, stream>>>(A, Wcat, bcat, Y);
        scan_kernel<<<B_, 256, 0, stream>>>(A, Y);
    } else if (ws_size >= needY) {
        float* Y = (float*)d_ws;
        gemm_kernel<<<1024, 256, 0, stream>>>(A, Y);
        scan_kernel<<<B_, 256, 0, stream>>>(A, Y);
    } else {
        phon_mono<<<B_, 256, 0, stream>>>(A);
    }
}

// Round 5
// 293.643 us; speedup vs baseline: 3.2860x; 1.0607x over previous
//
#include <hip/hip_runtime.h>

// Problem constants: B=2048, F=64, R=32, P=16, C=128, TAU=2.0
#define B_ 2048
#define NTOT 7426
#define YSTRIDE 7432
#define WSTRIDE 8192

typedef unsigned short u16;
typedef unsigned int   u32;
typedef __attribute__((ext_vector_type(2))) float v2f;

__device__ __forceinline__ float bfu(u16 u) {
    u32 i = ((u32)u) << 16; float f; __builtin_memcpy(&f, &i, 4); return f;
}
__device__ __forceinline__ float bflo(u32 w) {
    u32 i = w << 16; float f; __builtin_memcpy(&f, &i, 4); return f;
}
__device__ __forceinline__ float bfhi(u32 w) {
    u32 i = w & 0xffff0000u; float f; __builtin_memcpy(&f, &i, 4); return f;
}
__device__ __forceinline__ u16 f2bf(float v) {
    u32 iv; __builtin_memcpy(&iv, &v, 4);
    u32 r = (iv + 0x7fffu + ((iv >> 16) & 1u)) >> 16;
    return (u16)r;
}
__device__ __forceinline__ float sigm(float x) { return 1.f / (1.f + __expf(-x)); }
__device__ __forceinline__ float lsg(float x) {
    return fminf(x, 0.f) - log1pf(__expf(-fabsf(x)));
}

template<bool F32> __device__ __forceinline__ float LD(const void* p, int e) {
    if (F32) return ((const float*)p)[e];
    return bfu(((const u16*)p)[e]);
}
template<bool F32> __device__ __forceinline__ float2 LD2(const void* p, int e) { // e even
    if (F32) { const float* q = (const float*)p; return make_float2(q[e], q[e + 1]); }
    u32 w = ((const u32*)p)[e >> 1];
    return make_float2(bflo(w), bfhi(w));
}
template<bool F32> __device__ __forceinline__ float4 LD4(const void* p, int e) { // e%4==0
    if (F32) return ((const float4*)p)[e >> 2];
    uint2 w = ((const uint2*)p)[e >> 2];
    return make_float4(bflo(w.x), bfhi(w.x), bflo(w.y), bfhi(w.y));
}
template<bool F32> __device__ __forceinline__ void ST(void* p, int e, float v) {
    if (F32) ((float*)p)[e] = v; else ((u16*)p)[e] = f2bf(v);
}

struct Args {
    const void *form, *ctx;
    const void *mod_W, *mod_b, *wch_W, *wch_b, *wdl_W, *wdl_b, *wep_W, *wep_b;
    const void *vch_W, *vch_b, *vep_W, *vep_b;
    const void *wnc_W, *wnc_b, *wnd_W, *wnd_b, *wne_W, *wne_b;
    const void *m_W, *m_Wb, *mb_W, *mb_b;
    void* outp;
};

// dtype probe: block-uniform, deterministic. Returns 1 if inputs are fp32.
__device__ __forceinline__ int probe_is_f32(const void* ctx, int t, int* flag_s) {
    if (t == 0) {
        int sane = 0;
        const u16* q = (const u16*)ctx;
        for (int i = 0; i < 64; ++i) {
            u16 u = q[2 * i];
            int ex = (u >> 7) & 0xFF;
            sane += (u == 0 || (ex >= 112 && ex <= 143)) ? 1 : 0;
        }
        *flag_s = (sane < 32) ? 1 : 0;
    }
    __syncthreads();
    return *flag_s;
}

// ============================================================================
// Column layout (NTOT=7426, padded to WSTRIDE=8192):
//  [0,96)    mod       [96,1120)  wch       [1120,2144) vch
//  [2144,4192) vepI (n=2144+2u+s -> vep col 4u+2s, u=p*64+f)
//  [4192,7264) Wk (k*1024 + p*64 + f)       [7264,7312) bk (k*16+p)
//  [7312,7344) wepI (n=7312+2u+s -> wep col 4u+2s)
//  [7344,7360) wdl   [7360,7424) wnc   [7424] wnd   [7425] wne  [7426,8192) 0
// ============================================================================

// ---------------- Kernel 0: repack weights -> Wcat[128][WSTRIDE], bcat ------
template<bool F32>
__device__ void repack_body(int idx, const Args& A, float* Wcat, float* bcat) {
    int n = idx & (WSTRIDE - 1);
    int c = idx >> 13;
    float w = 0.f, bb = 0.f;
    if (n < 96)        { w = LD<F32>(A.mod_W, c * 96 + n);   bb = LD<F32>(A.mod_b, n); }
    else if (n < 1120) { int j = n - 96;   w = LD<F32>(A.wch_W, c * 1024 + j); bb = LD<F32>(A.wch_b, j); }
    else if (n < 2144) { int j = n - 1120; w = LD<F32>(A.vch_W, c * 1024 + j); bb = LD<F32>(A.vch_b, j); }
    else if (n < 4192) { int i = n - 2144; int col = 4 * (i >> 1) + 2 * (i & 1);
                         w = LD<F32>(A.vep_W, c * 4096 + col); bb = LD<F32>(A.vep_b, col); }
    else if (n < 7264) { int i = n - 4192; int k = i >> 10, j = i & 1023;
                         w = LD<F32>(A.m_W, (k * 128 + c) * 1024 + j); bb = LD<F32>(A.m_Wb, k * 1024 + j); }
    else if (n < 7312) { int i = n - 7264; int k = i >> 4, p = i & 15;
                         w = LD<F32>(A.mb_W, (k * 128 + c) * 16 + p); bb = LD<F32>(A.mb_b, k * 16 + p); }
    else if (n < 7344) { int i = n - 7312; int col = 4 * (i >> 1) + 2 * (i & 1);
                         w = LD<F32>(A.wep_W, c * 64 + col); bb = LD<F32>(A.wep_b, col); }
    else if (n < 7360) { int j = n - 7344; w = LD<F32>(A.wdl_W, c * 16 + j); bb = LD<F32>(A.wdl_b, j); }
    else if (n < 7424) { int j = n - 7360; w = LD<F32>(A.wnc_W, c * 64 + j); bb = LD<F32>(A.wnc_b, j); }
    else if (n == 7424){ w = LD<F32>(A.wnd_W, c); bb = LD<F32>(A.wnd_b, 0); }
    else if (n == 7425){ w = LD<F32>(A.wne_W, c); bb = LD<F32>(A.wne_b, 0); }
    Wcat[idx] = w;
    if (c == 0) bcat[n] = bb;
}

__global__ __launch_bounds__(256) void repack_kernel(Args A, float* Wcat, float* bcat) {
    __shared__ int dt_s;
    const int t = threadIdx.x;
    int isf32 = probe_is_f32(A.ctx, t, &dt_s);
    int idx = blockIdx.x * 256 + t;
    if (isf32) repack_body<true>(idx, A, Wcat, bcat);
    else       repack_body<false>(idx, A, Wcat, bcat);
}

// ---------------- Kernel 1: no-LDS GEMM  Y = ctx @ Wcat + bcat --------------
// block: 16 rows x 1024 cols; thread: 16 rows x 4 cols. ctx addresses are
// wave-uniform -> scalar (K$) loads; no LDS, no __syncthreads.
template<bool F32>
__device__ void gemm3_body(int t, int blk, const void* __restrict__ ctx,
                           const float* __restrict__ Wcat, const float* __restrict__ bcat,
                           float* __restrict__ Y) {
    const int cb = blk & 7;
    const int mb = (blk >> 3) * 16;
    const int n0 = cb * 1024 + 4 * t;
    const float4* W4 = (const float4*)Wcat;       // [c][WSTRIDE/4]
    const int wcol = n0 >> 2;

    float4 bv = *(const float4*)(bcat + n0);
    v2f acc[16][2];
    #pragma unroll
    for (int m = 0; m < 16; ++m) {
        acc[m][0].x = bv.x; acc[m][0].y = bv.y;
        acc[m][1].x = bv.z; acc[m][1].y = bv.w;
    }

    float4 w[4];
    #pragma unroll
    for (int j = 0; j < 4; ++j) w[j] = W4[(size_t)j * 2048 + wcol];

    #pragma unroll 1
    for (int c4 = 0; c4 < 128; c4 += 4) {
        float4 wn[4];
        if (c4 + 4 < 128) {
            #pragma unroll
            for (int j = 0; j < 4; ++j) wn[j] = W4[(size_t)(c4 + 4 + j) * 2048 + wcol];
        }
        #pragma unroll
        for (int m = 0; m < 16; ++m) {
            // uniform address -> scalar load (all lanes same value)
            float4 cv = LD4<F32>(ctx, (mb + m) * 128 + c4);
            float cs[4] = {cv.x, cv.y, cv.z, cv.w};
            #pragma unroll
            for (int j = 0; j < 4; ++j) {
                v2f cc; cc.x = cs[j]; cc.y = cs[j];
                v2f w01; w01.x = w[j].x; w01.y = w[j].y;
                v2f w23; w23.x = w[j].z; w23.y = w[j].w;
                acc[m][0] += cc * w01;
                acc[m][1] += cc * w23;
            }
        }
        #pragma unroll
        for (int j = 0; j < 4; ++j) w[j] = wn[j];
    }

    if (n0 < YSTRIDE) {
        #pragma unroll
        for (int m = 0; m < 16; ++m) {
            float4 s;
            s.x = acc[m][0].x; s.y = acc[m][0].y; s.z = acc[m][1].x; s.w = acc[m][1].y;
            *(float4*)(Y + (size_t)(mb + m) * YSTRIDE + n0) = s;
        }
    }
}

__global__ __launch_bounds__(256, 4) void gemm3_kernel(Args A, const float* Wcat,
                                                       const float* bcat, float* Y) {
    __shared__ int dt_s;
    const int t = threadIdx.x, blk = blockIdx.x;
    int isf32 = probe_is_f32(A.ctx, t, &dt_s);
    if (isf32) gemm3_body<true>(t, blk, A.ctx, Wcat, bcat, Y);
    else       gemm3_body<false>(t, blk, A.ctx, Wcat, bcat, Y);
}

// ---------------- Mid-tier GEMM (round-3, branchy; used only if ws tight) ---
struct PD { const void* p0; int off; int st; int mode; float b0, b1; };

template<bool F32>
__device__ __forceinline__ void resolve(const Args& A, int n0, PD& d) {
    if (n0 < 96) {
        d.mode = 0; d.p0 = A.mod_W; d.off = n0; d.st = 96;
        float2 b = LD2<F32>(A.mod_b, n0); d.b0 = b.x; d.b1 = b.y;
    } else if (n0 < 1120) {
        int j = n0 - 96;
        d.mode = 0; d.p0 = A.wch_W; d.off = j; d.st = 1024;
        float2 b = LD2<F32>(A.wch_b, j); d.b0 = b.x; d.b1 = b.y;
    } else if (n0 < 2144) {
        int j = n0 - 1120;
        d.mode = 0; d.p0 = A.vch_W; d.off = j; d.st = 1024;
        float2 b = LD2<F32>(A.vch_b, j); d.b0 = b.x; d.b1 = b.y;
    } else if (n0 < 4192) {
        int u = (n0 - 2144) >> 1;
        d.mode = 1; d.p0 = A.vep_W; d.off = 4 * u; d.st = 4096;
        float4 b = LD4<F32>(A.vep_b, 4 * u); d.b0 = b.x; d.b1 = b.z;
    } else if (n0 < 7264) {
        int i = n0 - 4192; int k = i >> 10, j = i & 1023;
        d.mode = 0; d.p0 = A.m_W; d.off = k * 131072 + j; d.st = 1024;
        float2 b = LD2<F32>(A.m_Wb, k * 1024 + j); d.b0 = b.x; d.b1 = b.y;
    } else if (n0 < 7312) {
        int i = n0 - 7264; int k = i >> 4, p = i & 15;
        d.mode = 0; d.p0 = A.mb_W; d.off = k * 2048 + p; d.st = 16;
        float2 b = LD2<F32>(A.mb_b, k * 16 + p); d.b0 = b.x; d.b1 = b.y;
    } else if (n0 < 7344) {
        int u = (n0 - 7312) >> 1;
        d.mode = 1; d.p0 = A.wep_W; d.off = 4 * u; d.st = 64;
        float4 b = LD4<F32>(A.wep_b, 4 * u); d.b0 = b.x; d.b1 = b.z;
    } else if (n0 < 7360) {
        int j = n0 - 7344;
        d.mode = 0; d.p0 = A.wdl_W; d.off = j; d.st = 16;
        float2 b = LD2<F32>(A.wdl_b, j); d.b0 = b.x; d.b1 = b.y;
    } else if (n0 < 7424) {
        int j = n0 - 7360;
        d.mode = 0; d.p0 = A.wnc_W; d.off = j; d.st = 64;
        float2 b = LD2<F32>(A.wnc_b, j); d.b0 = b.x; d.b1 = b.y;
    } else if (n0 == 7424) {
        d.mode = 2; d.p0 = A.wnd_W; d.off = 0; d.st = 1;
        d.b0 = LD<F32>(A.wnd_b, 0); d.b1 = LD<F32>(A.wne_b, 0);
    } else {
        d.mode = 3; d.p0 = A.mod_W; d.off = 0; d.st = 0; d.b0 = 0.f; d.b1 = 0.f;
    }
}

template<bool F32>
__device__ __forceinline__ v2f fetchw(const PD& d, const Args& A, int c) {
    if (d.mode == 0) {
        float2 w = LD2<F32>(d.p0, d.off + c * d.st);
        v2f r; r.x = w.x; r.y = w.y; return r;
    } else if (d.mode == 1) {
        float4 q = LD4<F32>(d.p0, d.off + c * d.st);
        v2f r; r.x = q.x; r.y = q.z; return r;
    } else if (d.mode == 2) {
        v2f r; r.x = LD<F32>(A.wnd_W, c); r.y = LD<F32>(A.wne_W, c); return r;
    }
    v2f r; r.x = 0.f; r.y = 0.f; return r;
}

template<bool F32>
__device__ void gemm_body(float (*ctx_s)[128], int t, int blk, const Args& A, float* Y) {
    const int cb = blk & 3;
    const int mb = (blk >> 2) * 8;
    {
        int m = t >> 5, c0 = (t & 31) * 4;
        float4 v = LD4<F32>(A.ctx, (mb + m) * 128 + c0);
        ctx_s[m][c0] = v.x; ctx_s[m][c0 + 1] = v.y; ctx_s[m][c0 + 2] = v.z; ctx_s[m][c0 + 3] = v.w;
    }
    __syncthreads();
    PD d[4]; int n0[4];
    #pragma unroll
    for (int i = 0; i < 4; ++i) { n0[i] = cb * 2048 + i * 512 + 2 * t; resolve<F32>(A, n0[i], d[i]); }
    v2f acc[4][8];
    #pragma unroll
    for (int i = 0; i < 4; ++i)
        #pragma unroll
        for (int m = 0; m < 8; ++m) { acc[i][m].x = d[i].b0; acc[i][m].y = d[i].b1; }
    for (int c4 = 0; c4 < 32; ++c4) {
        float cv[8][4];
        #pragma unroll
        for (int m = 0; m < 8; ++m) *(float4*)cv[m] = *(const float4*)&ctx_s[m][c4 * 4];
        #pragma unroll
        for (int j = 0; j < 4; ++j) {
            int c = c4 * 4 + j;
            v2f w[4];
            #pragma unroll
            for (int i = 0; i < 4; ++i) w[i] = fetchw<F32>(d[i], A, c);
            #pragma unroll
            for (int m = 0; m < 8; ++m) {
                v2f cvv; cvv.x = cv[m][j]; cvv.y = cv[m][j];
                #pragma unroll
                for (int i = 0; i < 4; ++i) acc[i][m] += cvv * w[i];
            }
        }
    }
    #pragma unroll
    for (int i = 0; i < 4; ++i) {
        if (d[i].mode < 3) {
            #pragma unroll
            for (int m = 0; m < 8; ++m) {
                float2 s; s.x = acc[i][m].x; s.y = acc[i][m].y;
                *(float2*)(Y + (size_t)(mb + m) * YSTRIDE + n0[i]) = s;
            }
        }
    }
}

__global__ __launch_bounds__(256) void gemm_kernel(Args A, float* Y) {
    __shared__ float ctx_s[8][128];
    __shared__ int dt_s;
    const int t = threadIdx.x, blk = blockIdx.x;
    int isf32 = probe_is_f32(A.ctx, t, &dt_s);
    if (isf32) gemm_body<true>(ctx_s, t, blk, A, Y);
    else       gemm_body<false>(ctx_s, t, blk, A, Y);
}

// ---------------- Kernel 2: match + xtab(reg-cached) + parallel-gated scan --
struct __align__(16) ScanSmem {
    float U[6144];          // Wk(0..3071 p64) bk@3072(48) modl@3120(96); then xtab
    float V[3072];          // wch@0 vch@1024 rlI@2048(1024); then gtab(3072)
    float form_s[64 * 33];  // [f][r] pitch 33
    float match_s[512];     // [p][r]; later ck@0(96) pos@128(96)
    float wnc_s[64];
    float wep0_s[16], wep2_s[16], wdl_s[16];
    float coef_s[96];       // [sub][rs] (sub 0:ep0, 1:deln, 2:ep2)
    float sc_s[2];          // {w_nodeln, w_noepen}
};

template<bool F32>
__device__ void scan_body(ScanSmem& S, int t, int b, const Args& A, const float* __restrict__ Y) {
    float* Wk_s = S.U;
    float* bk_s = S.U + 3072;
    float* modl = S.U + 3120;
    float* xtab = S.U;             // overlay after match phase
    float* wch_s = S.V;
    float* vch_s = S.V + 1024;
    float* rlI   = S.V + 2048;     // relu(match*wep) pairs, written pre-xtab
    float* gtab  = S.V;            // overlay in phase D

    const float* Yr = Y + (size_t)b * YSTRIDE;
    const float4* Y4 = (const float4*)Yr;

    const int f_own = t & 63;
    const int fq    = t >> 6;

    // ---- register-cache vep pairs straight from global Y (coalesced b64) ---
    const float2* vep2p = (const float2*)(Yr + 2144);
    v2f vepf[16];
    #pragma unroll
    for (int p = 0; p < 16; ++p) {
        float2 v = vep2p[p * 64 + f_own];
        vepf[p].x = v.x; vepf[p].y = v.y;
    }

    // ---- stage form + Y segments into LDS ----
    {
        int e0 = b * 2048 + t * 8;
        float4 x = LD4<F32>(A.form, e0);
        float4 y = LD4<F32>(A.form, e0 + 4);
        int f = t >> 2, r0 = (t & 3) * 8;
        float* dst = S.form_s + f * 33 + r0;
        dst[0] = x.x; dst[1] = x.y; dst[2] = x.z; dst[3] = x.w;
        dst[4] = y.x; dst[5] = y.y; dst[6] = y.z; dst[7] = y.w;
    }
    for (int i = t; i < 768; i += 256) ((float4*)Wk_s)[i] = Y4[1048 + i];    // Wk @4192
    if (t < 12) ((float4*)bk_s)[t] = Y4[1816 + t];                           // bk @7264
    if (t < 24) ((float4*)modl)[t] = Y4[t];                                  // mod @0
    ((float4*)wch_s)[t] = Y4[24 + t];                                        // wch @96
    ((float4*)vch_s)[t] = Y4[280 + t];                                       // vch @1120
    if (t < 16) {
        S.wep0_s[t] = Yr[7312 + 2 * t];
        S.wep2_s[t] = Yr[7312 + 2 * t + 1];
        S.wdl_s[t]  = Yr[7344 + t];
    } else if (t >= 32 && t < 96) {
        S.wnc_s[t - 32] = __expf(Yr[7360 + (t - 32)]);
    } else if (t >= 96 && t < 98) {
        S.sc_s[t - 96] = __expf(Yr[7424 + (t - 96)]);
    }
    __syncthreads();

    // ---- softmax(6) on mod ----
    if (t < 16) {
        float v[6]; float mx = -1e30f;
        #pragma unroll
        for (int j = 0; j < 6; ++j) { v[j] = modl[t * 6 + j]; mx = fmaxf(mx, v[j]); }
        float s = 0.f;
        #pragma unroll
        for (int j = 0; j < 6; ++j) { v[j] = __expf(v[j] - mx); s += v[j]; }
        float inv = 1.f / s;
        #pragma unroll
        for (int j = 0; j < 6; ++j) modl[t * 6 + j] = v[j] * inv;
    }
    __syncthreads();

    // ---- mod scaling + phase C (match) ----
    if (t < 16) {
        S.wep0_s[t] *= modl[t * 6 + 2];
        S.wep2_s[t] *= modl[t * 6 + 4];
        S.wdl_s[t]  *= modl[t * 6 + 1];
    }
    for (int i = t; i < 1024; i += 256) wch_s[i] *= modl[(i >> 6) * 6];

    const int my_r = t & 31;
    #pragma unroll 1
    for (int it = 0; it < 2; ++it) {
        int idx = t + 256 * it;
        int p = idx >> 5, r = idx & 31;
        float s0 = bk_s[p], s1 = bk_s[16 + p], s2 = bk_s[32 + p];
        const float4* w0 = (const float4*)(Wk_s + p * 64);
        const float4* w1 = (const float4*)(Wk_s + (16 + p) * 64);
        const float4* w2 = (const float4*)(Wk_s + (32 + p) * 64);
        for (int f4 = 0; f4 < 16; ++f4) {
            float a0[4], a1[4], a2[4];
            *(float4*)a0 = w0[f4]; *(float4*)a1 = w1[f4]; *(float4*)a2 = w2[f4];
            #pragma unroll
            for (int j = 0; j < 4; ++j) {
                int f = f4 * 4 + j;
                float f0 = S.form_s[f * 33 + r];
                float fm = __shfl_up(f0, 1, 32);   if (r == 0)  fm = 0.f;
                float fp = __shfl_down(f0, 1, 32); if (r == 31) fp = 0.f;
                s0 += a0[j] * fm; s1 += a1[j] * f0; s2 += a2[j] * fp;
            }
        }
        S.match_s[p * 32 + r] = __expf(lsg(s0) + lsg(s1) + lsg(s2));
    }
    __syncthreads();

    // ---- coef + rlI precompute ----
    if (t < 96) {
        int sub = t >> 5, r = t & 31;
        const float* w = (sub == 0) ? S.wep0_s : (sub == 1) ? S.wdl_s : S.wep2_s;
        float s = 0.f;
        for (int p = 0; p < 16; ++p) s += S.match_s[p * 32 + r] * w[p];
        float cf;
        if (sub == 1) cf = 1.f - sigm(s - S.sc_s[0]);   // 1 - p_deln
        else          cf = sigm(s - S.sc_s[1]);         // p_epen
        S.coef_s[sub * 32 + r] = cf;
    }
    for (int i = t; i < 512; i += 256) {
        int p = i >> 5, r = i & 31;
        float m = S.match_s[p * 32 + r];
        rlI[2 * i]     = fmaxf(m * S.wep0_s[p], 0.f);
        rlI[2 * i + 1] = fmaxf(m * S.wep2_s[p], 0.f);
    }
    // register-cache f-slices (wch already mod-scaled pre-barrier)
    float wchf[16], vchf[16];
    #pragma unroll
    for (int p = 0; p < 16; ++p) {
        wchf[p] = wch_s[p * 64 + f_own];
        vchf[p] = vch_s[p * 64 + f_own];
    }
    const float wncf = S.wnc_s[f_own];
    __syncthreads();

    // ---- xtab: per-thread fixed f, 8 rs values; sub0+sub2 fused via pk_fma -
    #pragma unroll 1
    for (int j = 0; j < 8; ++j) {
        int rs = fq * 8 + j;                       // wave-uniform
        v2f v02; v02.x = 0.f; v02.y = 0.f;
        float sum = 0.f, vs1 = 0.f;
        const v2f* rlp = (const v2f*)(rlI + 2 * rs);
        #pragma unroll
        for (int p = 0; p < 16; ++p) {
            v2f rl = rlp[p * 32];                  // broadcast b64
            v02 += rl * vepf[p];
            float m = S.match_s[p * 32 + rs];      // broadcast b32
            float wc = m * wchf[p];
            sum += wc;
            vs1 += fmaxf(wc, 0.f) * vchf[p];
        }
        float pch = sigm(sum - wncf);
        float si  = S.form_s[f_own * 33 + rs];
        xtab[0 * 2048 + rs * 64 + f_own] = v02.x;
        xtab[1 * 2048 + rs * 64 + f_own] = si + pch * (vs1 - si);
        xtab[2 * 2048 + rs * 64 + f_own] = v02.y;
    }
    __syncthreads();

    // ---- k-ordered coefs (k = rs*3+sub) + exclusive prefix (posn) ----
    float* ck_s  = S.match_s;        // match dead after xtab
    float* pos_s = S.match_s + 128;
    if (t < 96) ck_s[t] = S.coef_s[(t % 3) * 32 + (t / 3)];
    __syncthreads();
    if (t < 64) {
        float a = ck_s[t];
        float a0 = a;
        #pragma unroll
        for (int d = 1; d < 64; d <<= 1) { float v = __shfl_up(a, d, 64); if (t >= d) a += v; }
        pos_s[t] = a - a0;                          // exclusive prefix
        float carry = __shfl(a, 63, 64);            // inclusive sum of first 64
        float b2 = (t < 32) ? ck_s[64 + t] : 0.f;
        float c2 = b2;
        #pragma unroll
        for (int d = 1; d < 32; d <<= 1) { float v = __shfl_up(c2, d, 32); if ((t & 31) >= d) c2 += v; }
        if (t < 32) pos_s[64 + t] = carry + c2 - b2;
    }
    __syncthreads();

    // ---- gtab[k][r]: all 96 softmax-gates in parallel (overlays V) ----
    #pragma unroll 1
    for (int i = 0; i < 12; ++i) {
        int idx = t + 256 * i;                      // k = idx>>5, r = idx&31
        int k = idx >> 5, r = idx & 31;
        float posn = pos_s[k];
        float pc = fminf(posn, 31.f);
        float ci = floorf(pc + 0.5f);
        float dmin = posn - ci;
        float dd = posn - (float)r;
        float eo = __expf(-2.f * (dd * dd - dmin * dmin));   // exact, max-subtracted
        float Z = eo;
        Z += __shfl_xor(Z, 1, 32);
        Z += __shfl_xor(Z, 2, 32);
        Z += __shfl_xor(Z, 4, 32);
        Z += __shfl_xor(Z, 8, 32);
        Z += __shfl_xor(Z, 16, 32);
        gtab[idx] = ck_s[k] * eo / Z;
    }
    __syncthreads();

    // ---- phase D: pure-throughput blend ----
    const int fgrp = t >> 5;
    v2f o01, o23, o45, o67;
    o01 = 0.f; o23 = 0.f; o45 = 0.f; o67 = 0.f;
    #pragma unroll 1
    for (int rs = 0; rs < 32; ++rs) {
        #pragma unroll
        for (int sub = 0; sub < 3; ++sub) {
            float g = gtab[(rs * 3 + sub) * 32 + my_r];
            v2f gv; gv.x = g; gv.y = g;
            const float4* xb = (const float4*)(xtab + sub * 2048 + rs * 64 + fgrp * 8);
            float4 xa = xb[0], xc = xb[1];
            v2f x01, x23, x45, x67;
            x01.x = xa.x; x01.y = xa.y; x23.x = xa.z; x23.y = xa.w;
            x45.x = xc.x; x45.y = xc.y; x67.x = xc.z; x67.y = xc.w;
            o01 += gv * (x01 - o01);
            o23 += gv * (x23 - o23);
            o45 += gv * (x45 - o45);
            o67 += gv * (x67 - o67);
        }
    }

    float oreg[8] = {o01.x, o01.y, o23.x, o23.y, o45.x, o45.y, o67.x, o67.y};
    #pragma unroll
    for (int i = 0; i < 8; ++i) {
        ST<F32>(A.outp, b * 2048 + (fgrp * 8 + i) * 32 + my_r, oreg[i]);
    }
}

__global__ __launch_bounds__(256) void scan_kernel(Args A, const float* Y) {
    __shared__ ScanSmem S;
    __shared__ int dt_s;
    const int t = threadIdx.x, b = blockIdx.x;
    int isf32 = probe_is_f32(A.ctx, t, &dt_s);
    if (isf32) scan_body<true>(S, t, b, A, Y);
    else       scan_body<false>(S, t, b, A, Y);
}

// ---------------- Last-resort monolithic fallback (round-2, proven) ---------
struct Smem {
    float U[6144];
    float form_s[64 * 33];
    float match_s[512];
    float wch_s[1024];
    float vch_s[1024];
    float vep0_s[1024];
    float vep2_s[1024];
    float wep0_s[16], wep2_s[16], wdl_s[16];
    float wnc_s[64];
    float sc_s[2];
    float ssum_s[96];
};

template<bool F32>
__device__ void mono_body(Smem& S, int t, int b, const Args& A) {
    float* c_s  = S.U;
    float* modl = S.U + 128;
    float* Wk_s = S.U + 224;
    float* bk_s = S.U + 3344;
    float* xtab = S.U;

    if (t < 128) c_s[t] = LD<F32>(A.ctx, b * 128 + t);
    {
        int e0 = b * 2048 + t * 8;
        float4 x = LD4<F32>(A.form, e0);
        float4 y = LD4<F32>(A.form, e0 + 4);
        int f = t >> 2, r0 = (t & 3) * 8;
        float* dst = S.form_s + f * 33 + r0;
        dst[0] = x.x; dst[1] = x.y; dst[2] = x.z; dst[3] = x.w;
        dst[4] = y.x; dst[5] = y.y; dst[6] = y.z; dst[7] = y.w;
    }
    __syncthreads();
    if (t < 96) {
        float a = LD<F32>(A.mod_b, t);
        for (int cc = 0; cc < 128; ++cc) a += c_s[cc] * LD<F32>(A.mod_W, cc * 96 + t);
        modl[t] = a;
    }
    __syncthreads();
    if (t < 16) {
        float v[6]; float mx = -1e30f;
        #pragma unroll
        for (int j = 0; j < 6; ++j) { v[j] = modl[t * 6 + j]; mx = fmaxf(mx, v[j]); }
        float s = 0.f;
        #pragma unroll
        for (int j = 0; j < 6; ++j) { v[j] = __expf(v[j] - mx); s += v[j]; }
        float inv = 1.f / s;
        #pragma unroll
        for (int j = 0; j < 6; ++j) modl[t * 6 + j] = v[j] * inv;
    }
    __syncthreads();
    for (int j = t; j < 512; j += 256) {
        int n0 = j * 2;
        float2 bb = LD2<F32>(A.wch_b, n0);
        float a0 = bb.x, a1 = bb.y;
        for (int cc = 0; cc < 128; ++cc) {
            float2 w = LD2<F32>(A.wch_W, cc * 1024 + n0); float cv = c_s[cc];
            a0 += cv * w.x; a1 += cv * w.y;
        }
        int p = n0 >> 6; float sc = modl[p * 6 + 0];
        S.wch_s[n0] = sc * a0; S.wch_s[n0 + 1] = sc * a1;
    }
    for (int j = t; j < 512; j += 256) {
        int n0 = j * 2;
        float2 bb = LD2<F32>(A.vch_b, n0);
        float a0 = bb.x, a1 = bb.y;
        for (int cc = 0; cc < 128; ++cc) {
            float2 w = LD2<F32>(A.vch_W, cc * 1024 + n0); float cv = c_s[cc];
            a0 += cv * w.x; a1 += cv * w.y;
        }
        S.vch_s[n0] = a0; S.vch_s[n0 + 1] = a1;
    }
    for (int u = t; u < 1024; u += 256) {
        int n0 = u * 4;
        float4 bb = LD4<F32>(A.vep_b, n0);
        float a0 = bb.x, a2 = bb.z;
        for (int cc = 0; cc < 128; ++cc) {
            float4 w = LD4<F32>(A.vep_W, cc * 4096 + n0); float cv = c_s[cc];
            a0 += cv * w.x; a2 += cv * w.z;
        }
        S.vep0_s[u] = a0; S.vep2_s[u] = a2;
    }
    for (int j = t; j < 1536; j += 256) {
        int k  = j >> 9;
        int jj = j & 511;
        int n0 = jj * 2;
        float2 bb = LD2<F32>(A.m_Wb, k * 1024 + n0);
        float a0 = bb.x, a1 = bb.y;
        for (int cc = 0; cc < 128; ++cc) {
            float2 w = LD2<F32>(A.m_W, (k * 128 + cc) * 1024 + n0); float cv = c_s[cc];
            a0 += cv * w.x; a1 += cv * w.y;
        }
        int p = n0 >> 6, f = n0 & 63;
        Wk_s[(k * 16 + p) * 65 + f]     = a0;
        Wk_s[(k * 16 + p) * 65 + f + 1] = a1;
    }
    if (t < 16) {
        int n0 = t * 4;
        float4 bb = LD4<F32>(A.wep_b, n0);
        float a0 = bb.x, a2 = bb.z;
        for (int cc = 0; cc < 128; ++cc) {
            float4 w = LD4<F32>(A.wep_W, cc * 64 + n0); float cv = c_s[cc];
            a0 += cv * w.x; a2 += cv * w.z;
        }
        S.wep0_s[t] = modl[t * 6 + 2] * a0;
        S.wep2_s[t] = modl[t * 6 + 4] * a2;
    } else if (t < 32) {
        int p = t - 16;
        float a = LD<F32>(A.wdl_b, p);
        for (int cc = 0; cc < 128; ++cc) a += c_s[cc] * LD<F32>(A.wdl_W, cc * 16 + p);
        S.wdl_s[p] = modl[p * 6 + 1] * a;
    } else if (t < 96) {
        int f = t - 32;
        float a = LD<F32>(A.wnc_b, f);
        for (int cc = 0; cc < 128; ++cc) a += c_s[cc] * LD<F32>(A.wnc_W, cc * 64 + f);
        S.wnc_s[f] = __expf(a);
    } else if (t < 98) {
        const void* W  = (t == 96) ? A.wnd_W : A.wne_W;
        const void* bb = (t == 96) ? A.wnd_b : A.wne_b;
        float a = LD<F32>(bb, 0);
        for (int cc = 0; cc < 128; ++cc) a += c_s[cc] * LD<F32>(W, cc);
        S.sc_s[t - 96] = __expf(a);
    } else if (t < 146) {
        int i = t - 98;
        int k = i >> 4, p = i & 15;
        float a = LD<F32>(A.mb_b, k * 16 + p);
        for (int cc = 0; cc < 128; ++cc) a += c_s[cc] * LD<F32>(A.mb_W, (k * 128 + cc) * 16 + p);
        bk_s[i] = a;
    }
    __syncthreads();
    for (int idx = t; idx < 512; idx += 256) {
        int p = idx >> 5, r = idx & 31;
        float s0 = bk_s[p], s1 = bk_s[16 + p], s2 = bk_s[32 + p];
        const float* w0 = Wk_s + p * 65;
        const float* w1 = Wk_s + (16 + p) * 65;
        const float* w2 = Wk_s + (32 + p) * 65;
        for (int f = 0; f < 64; ++f) {
            const float* fr = S.form_s + f * 33 + r;
            float fm1 = (r > 0)  ? fr[-1] : 0.f;
            float f0  = fr[0];
            float fp1 = (r < 31) ? fr[1]  : 0.f;
            s0 += w0[f] * fm1; s1 += w1[f] * f0; s2 += w2[f] * fp1;
        }
        S.match_s[p * 32 + r] = __expf(lsg(s0) + lsg(s1) + lsg(s2));
    }
    __syncthreads();
    if (t < 96) {
        int which = t >> 5, r = t & 31;
        const float* w = (which == 0) ? S.wep0_s : (which == 1) ? S.wep2_s : S.wdl_s;
        float s = 0.f;
        for (int p = 0; p < 16; ++p) s += S.match_s[p * 32 + r] * w[p];
        S.ssum_s[which * 32 + r] = s;
    }
    #pragma unroll 1
    for (int q = 0; q < 24; ++q) {
        int idx = t + 256 * q;
        int sub = idx >> 11;
        int rs  = (idx >> 6) & 31;
        int f   = idx & 63;
        float x;
        if (sub == 1) {
            float sum = 0.f, vs = 0.f;
            for (int p = 0; p < 16; ++p) {
                float wc = S.match_s[p * 32 + rs] * S.wch_s[p * 64 + f];
                sum += wc;
                vs  += fmaxf(wc, 0.f) * S.vch_s[p * 64 + f];
            }
            float pch = sigm(sum - S.wnc_s[f]);
            float si  = S.form_s[f * 33 + rs];
            x = si + pch * (vs - si);
        } else {
            const float* wep = (sub == 0) ? S.wep0_s : S.wep2_s;
            const float* vep = (sub == 0) ? S.vep0_s : S.vep2_s;
            float vs = 0.f;
            for (int p = 0; p < 16; ++p) {
                float w = S.match_s[p * 32 + rs] * wep[p];
                vs += fmaxf(w, 0.f) * vep[p * 64 + f];
            }
            x = vs;
        }
        xtab[idx] = x;
    }
    __syncthreads();
    const int my_r = t & 31;
    const int fgrp = t >> 5;
    float oreg[8];
    #pragma unroll
    for (int i = 0; i < 8; ++i) oreg[i] = 0.f;
    float posn = 0.f;
    const float wnd1v = S.sc_s[0];
    const float wne1v = S.sc_s[1];
    for (int rs = 0; rs < 32; ++rs) {
        #pragma unroll
        for (int sub = 0; sub < 3; ++sub) {
            float coef;
            if (sub == 1) coef = 1.f - sigm(S.ssum_s[64 + rs] - wnd1v);
            else          coef = sigm(S.ssum_s[(sub & 2) * 16 + rs] - wne1v);
            float pc = fminf(posn, 31.f);
            int ci = (int)(pc + 0.5f);
            int lo = ci - 4; if (lo < 0)  lo = 0;
            int hi = ci + 4; if (hi > 31) hi = 31;
            float dmin = posn - (float)ci;
            float mx = -2.f * dmin * dmin;
            float Z = 0.f, eo = 0.f;
            for (int r = lo; r <= hi; ++r) {
                float d = posn - (float)r;
                float e = __expf(-2.f * d * d - mx);
                Z += e;
                if (r == my_r) eo = e;
            }
            float g = coef * eo / Z;
            const float* xb = xtab + (sub * 2048 + rs * 64 + fgrp * 8);
            #pragma unroll
            for (int i = 0; i < 8; ++i) oreg[i] += g * (xb[i] - oreg[i]);
            posn += coef;
        }
    }
    #pragma unroll
    for (int i = 0; i < 8; ++i) {
        ST<F32>(A.outp, b * 2048 + (fgrp * 8 + i) * 32 + my_r, oreg[i]);
    }
}

__global__ __launch_bounds__(256) void phon_mono(Args A) {
    __shared__ Smem S;
    __shared__ int dt_s;
    const int t = threadIdx.x, b = blockIdx.x;
    int isf32 = probe_is_f32(A.ctx, t, &dt_s);
    if (isf32) mono_body<true>(S, t, b, A);
    else       mono_body<false>(S, t, b, A);
}

extern "C" void kernel_launch(void* const* d_in, const int* in_sizes, int n_in,
                              void* d_out, int out_size, void* d_ws, size_t ws_size,
                              hipStream_t stream) {
    Args A;
    A.form  = d_in[0];  A.ctx   = d_in[1];
    A.mod_W = d_in[2];  A.mod_b = d_in[3];
    A.wch_W = d_in[4];  A.wch_b = d_in[5];
    A.wdl_W = d_in[6];  A.wdl_b = d_in[7];
    A.wep_W = d_in[8];  A.wep_b = d_in[9];
    A.vch_W = d_in[10]; A.vch_b = d_in[11];
    A.vep_W = d_in[12]; A.vep_b = d_in[13];
    A.wnc_W = d_in[14]; A.wnc_b = d_in[15];
    A.wnd_W = d_in[16]; A.wnd_b = d_in[17];
    A.wne_W = d_in[18]; A.wne_b = d_in[19];
    A.m_W   = d_in[20]; A.m_Wb  = d_in[21];
    A.mb_W  = d_in[22]; A.mb_b  = d_in[23];
    A.outp  = d_out;

    const size_t needY = (size_t)B_ * YSTRIDE * sizeof(float);
    const size_t needW = needY + ((size_t)128 * WSTRIDE + WSTRIDE) * sizeof(float);
    if (ws_size >= needW) {
        float* Y    = (float*)d_ws;
        float* Wcat = Y + (size_t)B_ * YSTRIDE;
        float* bcat = Wcat + (size_t)128 * WSTRIDE;
        repack_kernel<<<(128 * WSTRIDE) / 256, 256, 0, stream>>>(A, Wcat, bcat);
        gemm3_kernel<<<1024, 256, 0, stream>>>(A, Wcat, bcat, Y);
        scan_kernel<<<B_, 256, 0, stream>>>(A, Y);
    } else if (ws_size >= needY) {
        float* Y = (float*)d_ws;
        gemm_kernel<<<1024, 256, 0, stream>>>(A, Y);
        scan_kernel<<<B_, 256, 0, stream>>>(A, Y);
    } else {
        phon_mono<<<B_, 256, 0, stream>>>(A);
    }
}

// Round 6
// 274.131 us; speedup vs baseline: 3.5199x; 1.0712x over previous
//
#include <hip/hip_runtime.h>

// Problem constants: B=2048, F=64, R=32, P=16, C=128, TAU=2.0
#define B_ 2048
#define NTOT 7426
#define YSTRIDE 7432
#define WSTRIDE 8192

typedef unsigned short u16;
typedef unsigned int   u32;
typedef __attribute__((ext_vector_type(2))) float v2f;

__device__ __forceinline__ float bfu(u16 u) {
    u32 i = ((u32)u) << 16; float f; __builtin_memcpy(&f, &i, 4); return f;
}
__device__ __forceinline__ float bflo(u32 w) {
    u32 i = w << 16; float f; __builtin_memcpy(&f, &i, 4); return f;
}
__device__ __forceinline__ float bfhi(u32 w) {
    u32 i = w & 0xffff0000u; float f; __builtin_memcpy(&f, &i, 4); return f;
}
__device__ __forceinline__ u16 f2bf(float v) {
    u32 iv; __builtin_memcpy(&iv, &v, 4);
    u32 r = (iv + 0x7fffu + ((iv >> 16) & 1u)) >> 16;
    return (u16)r;
}
__device__ __forceinline__ float sigm(float x) { return 1.f / (1.f + __expf(-x)); }
__device__ __forceinline__ float lsg(float x) {
    return fminf(x, 0.f) - log1pf(__expf(-fabsf(x)));
}

template<bool F32> __device__ __forceinline__ float LD(const void* p, int e) {
    if (F32) return ((const float*)p)[e];
    return bfu(((const u16*)p)[e]);
}
template<bool F32> __device__ __forceinline__ float2 LD2(const void* p, int e) { // e even
    if (F32) { const float* q = (const float*)p; return make_float2(q[e], q[e + 1]); }
    u32 w = ((const u32*)p)[e >> 1];
    return make_float2(bflo(w), bfhi(w));
}
template<bool F32> __device__ __forceinline__ float4 LD4(const void* p, int e) { // e%4==0
    if (F32) return ((const float4*)p)[e >> 2];
    uint2 w = ((const uint2*)p)[e >> 2];
    return make_float4(bflo(w.x), bfhi(w.x), bflo(w.y), bfhi(w.y));
}
template<bool F32> __device__ __forceinline__ void ST(void* p, int e, float v) {
    if (F32) ((float*)p)[e] = v; else ((u16*)p)[e] = f2bf(v);
}

struct Args {
    const void *form, *ctx;
    const void *mod_W, *mod_b, *wch_W, *wch_b, *wdl_W, *wdl_b, *wep_W, *wep_b;
    const void *vch_W, *vch_b, *vep_W, *vep_b;
    const void *wnc_W, *wnc_b, *wnd_W, *wnd_b, *wne_W, *wne_b;
    const void *m_W, *m_Wb, *mb_W, *mb_b;
    void* outp;
};

// dtype probe: block-uniform, deterministic. Returns 1 if inputs are fp32.
__device__ __forceinline__ int probe_is_f32(const void* ctx, int t, int* flag_s) {
    if (t == 0) {
        int sane = 0;
        const u16* q = (const u16*)ctx;
        for (int i = 0; i < 64; ++i) {
            u16 u = q[2 * i];
            int ex = (u >> 7) & 0xFF;
            sane += (u == 0 || (ex >= 112 && ex <= 143)) ? 1 : 0;
        }
        *flag_s = (sane < 32) ? 1 : 0;
    }
    __syncthreads();
    return *flag_s;
}

// ============================================================================
// Column layout (NTOT=7426, padded to WSTRIDE=8192):
//  [0,96)    mod       [96,1120)  wch       [1120,2144) vch
//  [2144,4192) vepI (n=2144+2u+s -> vep col 4u+2s, u=p*64+f)
//  [4192,7264) Wk (k*1024 + p*64 + f)       [7264,7312) bk (k*16+p)
//  [7312,7344) wepI (n=7312+2u+s -> wep col 4u+2s)
//  [7344,7360) wdl   [7360,7424) wnc   [7424] wnd   [7425] wne  [7426,8192) 0
// All segment boundaries are even -> pair-based processing is safe.
// ============================================================================
struct PD { const void* p0; int off; int st; int mode; float b0, b1; };

template<bool F32>
__device__ __forceinline__ void resolve(const Args& A, int n0, PD& d) {
    if (n0 < 96) {
        d.mode = 0; d.p0 = A.mod_W; d.off = n0; d.st = 96;
        float2 b = LD2<F32>(A.mod_b, n0); d.b0 = b.x; d.b1 = b.y;
    } else if (n0 < 1120) {
        int j = n0 - 96;
        d.mode = 0; d.p0 = A.wch_W; d.off = j; d.st = 1024;
        float2 b = LD2<F32>(A.wch_b, j); d.b0 = b.x; d.b1 = b.y;
    } else if (n0 < 2144) {
        int j = n0 - 1120;
        d.mode = 0; d.p0 = A.vch_W; d.off = j; d.st = 1024;
        float2 b = LD2<F32>(A.vch_b, j); d.b0 = b.x; d.b1 = b.y;
    } else if (n0 < 4192) {
        int u = (n0 - 2144) >> 1;
        d.mode = 1; d.p0 = A.vep_W; d.off = 4 * u; d.st = 4096;
        float4 b = LD4<F32>(A.vep_b, 4 * u); d.b0 = b.x; d.b1 = b.z;
    } else if (n0 < 7264) {
        int i = n0 - 4192; int k = i >> 10, j = i & 1023;
        d.mode = 0; d.p0 = A.m_W; d.off = k * 131072 + j; d.st = 1024;
        float2 b = LD2<F32>(A.m_Wb, k * 1024 + j); d.b0 = b.x; d.b1 = b.y;
    } else if (n0 < 7312) {
        int i = n0 - 7264; int k = i >> 4, p = i & 15;
        d.mode = 0; d.p0 = A.mb_W; d.off = k * 2048 + p; d.st = 16;
        float2 b = LD2<F32>(A.mb_b, k * 16 + p); d.b0 = b.x; d.b1 = b.y;
    } else if (n0 < 7344) {
        int u = (n0 - 7312) >> 1;
        d.mode = 1; d.p0 = A.wep_W; d.off = 4 * u; d.st = 64;
        float4 b = LD4<F32>(A.wep_b, 4 * u); d.b0 = b.x; d.b1 = b.z;
    } else if (n0 < 7360) {
        int j = n0 - 7344;
        d.mode = 0; d.p0 = A.wdl_W; d.off = j; d.st = 16;
        float2 b = LD2<F32>(A.wdl_b, j); d.b0 = b.x; d.b1 = b.y;
    } else if (n0 < 7424) {
        int j = n0 - 7360;
        d.mode = 0; d.p0 = A.wnc_W; d.off = j; d.st = 64;
        float2 b = LD2<F32>(A.wnc_b, j); d.b0 = b.x; d.b1 = b.y;
    } else if (n0 == 7424) {
        d.mode = 2; d.p0 = A.wnd_W; d.off = 0; d.st = 1;
        d.b0 = LD<F32>(A.wnd_b, 0); d.b1 = LD<F32>(A.wne_b, 0);
    } else {
        d.mode = 3; d.p0 = A.mod_W; d.off = 0; d.st = 0; d.b0 = 0.f; d.b1 = 0.f;
    }
}

template<bool F32>
__device__ __forceinline__ v2f fetchw(const PD& d, const Args& A, int c) {
    if (d.mode == 0) {
        float2 w = LD2<F32>(d.p0, d.off + c * d.st);
        v2f r; r.x = w.x; r.y = w.y; return r;
    } else if (d.mode == 1) {
        float4 q = LD4<F32>(d.p0, d.off + c * d.st);
        v2f r; r.x = q.x; r.y = q.z; return r;
    } else if (d.mode == 2) {
        v2f r; r.x = LD<F32>(A.wnd_W, c); r.y = LD<F32>(A.wne_W, c); return r;
    }
    v2f r; r.x = 0.f; r.y = 0.f; return r;
}

// ---------------- Kernel 0: pair repack weights -> Wcat[128][WSTRIDE] -------
template<bool F32>
__device__ void repack_body(int pid, const Args& A, float* Wcat, float* bcat) {
    int n0 = 2 * (pid & 4095);
    int c  = pid >> 12;
    PD d;
    resolve<F32>(A, n0, d);
    v2f w = fetchw<F32>(d, A, c);
    float2 s; s.x = w.x; s.y = w.y;
    *(float2*)(Wcat + (size_t)c * WSTRIDE + n0) = s;
    if (c == 0) { bcat[n0] = d.b0; bcat[n0 + 1] = d.b1; }
}

__global__ __launch_bounds__(256) void repack_kernel(Args A, float* Wcat, float* bcat) {
    __shared__ int dt_s;
    const int t = threadIdx.x;
    int isf32 = probe_is_f32(A.ctx, t, &dt_s);
    int pid = blockIdx.x * 256 + t;
    if (isf32) repack_body<true>(pid, A, Wcat, bcat);
    else       repack_body<false>(pid, A, Wcat, bcat);
}

// ---------------- Kernel 1: small-tile GEMM  Y = ctx @ Wcat + bcat ----------
// block: 8 rows x 1024 cols (grid 2048 = 256 bb x 8 cb); thread: 8 rows x 4
// cols. acc = 32 VGPR -> high occupancy; ctx tile in LDS (4 KB), all ds_reads
// fully address-uniform (broadcast).
template<bool F32>
__device__ void gemm4_body(float* ctx_s, int t, int blk, const void* __restrict__ ctx,
                           const float* __restrict__ Wcat, const float* __restrict__ bcat,
                           float* __restrict__ Y) {
    const int cb = blk & 7;
    const int mb = (blk >> 3) * 8;

    // stage ctx tile [8][128] = 256 float4
    {
        int m = t >> 5, c0 = (t & 31) * 4;
        float4 v = LD4<F32>(ctx, (mb + m) * 128 + c0);
        *(float4*)&ctx_s[m * 128 + c0] = v;
    }
    __syncthreads();

    const int n0 = cb * 1024 + 4 * t;
    const float4* W4 = (const float4*)Wcat;       // [c][WSTRIDE/4]
    const int wcol = n0 >> 2;

    float4 bv = *(const float4*)(bcat + n0);
    v2f acc[8][2];
    #pragma unroll
    for (int m = 0; m < 8; ++m) {
        acc[m][0].x = bv.x; acc[m][0].y = bv.y;
        acc[m][1].x = bv.z; acc[m][1].y = bv.w;
    }

    float4 w[4];
    #pragma unroll
    for (int j = 0; j < 4; ++j) w[j] = W4[(size_t)j * 2048 + wcol];

    #pragma unroll 1
    for (int c4 = 0; c4 < 128; c4 += 4) {
        float4 wn[4];
        if (c4 + 4 < 128) {
            #pragma unroll
            for (int j = 0; j < 4; ++j) wn[j] = W4[(size_t)(c4 + 4 + j) * 2048 + wcol];
        }
        #pragma unroll
        for (int m = 0; m < 8; ++m) {
            float4 cv = *(const float4*)&ctx_s[m * 128 + c4];   // uniform addr
            float cs[4] = {cv.x, cv.y, cv.z, cv.w};
            #pragma unroll
            for (int j = 0; j < 4; ++j) {
                v2f cc; cc.x = cs[j]; cc.y = cs[j];
                v2f w01; w01.x = w[j].x; w01.y = w[j].y;
                v2f w23; w23.x = w[j].z; w23.y = w[j].w;
                acc[m][0] += cc * w01;
                acc[m][1] += cc * w23;
            }
        }
        #pragma unroll
        for (int j = 0; j < 4; ++j) w[j] = wn[j];
    }

    if (n0 < YSTRIDE) {
        #pragma unroll
        for (int m = 0; m < 8; ++m) {
            float4 s;
            s.x = acc[m][0].x; s.y = acc[m][0].y; s.z = acc[m][1].x; s.w = acc[m][1].y;
            *(float4*)(Y + (size_t)(mb + m) * YSTRIDE + n0) = s;
        }
    }
}

__global__ __launch_bounds__(256) void gemm4_kernel(Args A, const float* Wcat,
                                                    const float* bcat, float* Y) {
    __shared__ float ctx_s[8 * 128];
    __shared__ int dt_s;
    const int t = threadIdx.x, blk = blockIdx.x;
    int isf32 = probe_is_f32(A.ctx, t, &dt_s);
    if (isf32) gemm4_body<true>(ctx_s, t, blk, A.ctx, Wcat, bcat, Y);
    else       gemm4_body<false>(ctx_s, t, blk, A.ctx, Wcat, bcat, Y);
}

// ---------------- Mid-tier GEMM (branchy, direct; used only if ws tight) ----
template<bool F32>
__device__ void gemm_body(float (*ctx_s)[128], int t, int blk, const Args& A, float* Y) {
    const int cb = blk & 3;
    const int mb = (blk >> 2) * 8;
    {
        int m = t >> 5, c0 = (t & 31) * 4;
        float4 v = LD4<F32>(A.ctx, (mb + m) * 128 + c0);
        ctx_s[m][c0] = v.x; ctx_s[m][c0 + 1] = v.y; ctx_s[m][c0 + 2] = v.z; ctx_s[m][c0 + 3] = v.w;
    }
    __syncthreads();
    PD d[4]; int n0[4];
    #pragma unroll
    for (int i = 0; i < 4; ++i) { n0[i] = cb * 2048 + i * 512 + 2 * t; resolve<F32>(A, n0[i], d[i]); }
    v2f acc[4][8];
    #pragma unroll
    for (int i = 0; i < 4; ++i)
        #pragma unroll
        for (int m = 0; m < 8; ++m) { acc[i][m].x = d[i].b0; acc[i][m].y = d[i].b1; }
    for (int c4 = 0; c4 < 32; ++c4) {
        float cv[8][4];
        #pragma unroll
        for (int m = 0; m < 8; ++m) *(float4*)cv[m] = *(const float4*)&ctx_s[m][c4 * 4];
        #pragma unroll
        for (int j = 0; j < 4; ++j) {
            int c = c4 * 4 + j;
            v2f w[4];
            #pragma unroll
            for (int i = 0; i < 4; ++i) w[i] = fetchw<F32>(d[i], A, c);
            #pragma unroll
            for (int m = 0; m < 8; ++m) {
                v2f cvv; cvv.x = cv[m][j]; cvv.y = cv[m][j];
                #pragma unroll
                for (int i = 0; i < 4; ++i) acc[i][m] += cvv * w[i];
            }
        }
    }
    #pragma unroll
    for (int i = 0; i < 4; ++i) {
        if (d[i].mode < 3) {
            #pragma unroll
            for (int m = 0; m < 8; ++m) {
                float2 s; s.x = acc[i][m].x; s.y = acc[i][m].y;
                *(float2*)(Y + (size_t)(mb + m) * YSTRIDE + n0[i]) = s;
            }
        }
    }
}

__global__ __launch_bounds__(256) void gemm_kernel(Args A, float* Y) {
    __shared__ float ctx_s[8][128];
    __shared__ int dt_s;
    const int t = threadIdx.x, blk = blockIdx.x;
    int isf32 = probe_is_f32(A.ctx, t, &dt_s);
    if (isf32) gemm_body<true>(ctx_s, t, blk, A, Y);
    else       gemm_body<false>(ctx_s, t, blk, A, Y);
}

// ---------------- Kernel 2: match + xtab + parallel-gated scan --------------
// LDS plan (39.8 KB -> 4 blocks/CU):
//   U[6144]: Wk@0(3072,p64) bk@3072(48) modl@3120(96) form@3312(2112,p33)
//            -> after match phase, U is overlaid by xtab[6144]
//            (form pre-read to regs: si[8]/thread before the xtab barrier)
//   V[3072]: wch@0(1024) vch@1024(1024) rlI@2048(1024) -> gtab[3072] in D
struct __align__(16) ScanSmem {
    float U[6144];
    float V[3072];
    float match_s[512];     // [p][r]; later ck@0(96) pos@128(96)
    float wnc_s[64];
    float wep0_s[16], wep2_s[16], wdl_s[16];
    float coef_s[96];       // [sub][rs] (sub 0:ep0, 1:deln, 2:ep2)
    float sc_s[2];          // {w_nodeln, w_noepen}
};

template<bool F32>
__device__ void scan_body(ScanSmem& S, int t, int b, const Args& A, const float* __restrict__ Y) {
    float* Wk_s   = S.U;
    float* bk_s   = S.U + 3072;
    float* modl   = S.U + 3120;
    float* form_s = S.U + 3312;    // pitch 33, 2112 floats (<= 6144-3312=2832)
    float* xtab   = S.U;           // overlay after match phase
    float* wch_s  = S.V;
    float* vch_s  = S.V + 1024;
    float* rlI    = S.V + 2048;    // relu(match*wep) pairs
    float* gtab   = S.V;           // overlay in phase D

    const float* Yr = Y + (size_t)b * YSTRIDE;
    const float4* Y4 = (const float4*)Yr;

    const int f_own = t & 63;
    const int fq    = t >> 6;

    // ---- register-cache vep pairs straight from global Y (coalesced b64) ---
    const float2* vep2p = (const float2*)(Yr + 2144);
    v2f vepf[16];
    #pragma unroll
    for (int p = 0; p < 16; ++p) {
        float2 v = vep2p[p * 64 + f_own];
        vepf[p].x = v.x; vepf[p].y = v.y;
    }

    // ---- stage form + Y segments into LDS ----
    {
        int e0 = b * 2048 + t * 8;
        float4 x = LD4<F32>(A.form, e0);
        float4 y = LD4<F32>(A.form, e0 + 4);
        int f = t >> 2, r0 = (t & 3) * 8;
        float* dst = form_s + f * 33 + r0;
        dst[0] = x.x; dst[1] = x.y; dst[2] = x.z; dst[3] = x.w;
        dst[4] = y.x; dst[5] = y.y; dst[6] = y.z; dst[7] = y.w;
    }
    for (int i = t; i < 768; i += 256) ((float4*)Wk_s)[i] = Y4[1048 + i];    // Wk @4192
    if (t < 12) ((float4*)bk_s)[t] = Y4[1816 + t];                           // bk @7264
    if (t < 24) ((float4*)modl)[t] = Y4[t];                                  // mod @0
    ((float4*)wch_s)[t] = Y4[24 + t];                                        // wch @96
    ((float4*)vch_s)[t] = Y4[280 + t];                                       // vch @1120
    if (t < 16) {
        S.wep0_s[t] = Yr[7312 + 2 * t];
        S.wep2_s[t] = Yr[7312 + 2 * t + 1];
        S.wdl_s[t]  = Yr[7344 + t];
    } else if (t >= 32 && t < 96) {
        S.wnc_s[t - 32] = __expf(Yr[7360 + (t - 32)]);
    } else if (t >= 96 && t < 98) {
        S.sc_s[t - 96] = __expf(Yr[7424 + (t - 96)]);
    }
    __syncthreads();

    // ---- softmax(6) on mod ----
    if (t < 16) {
        float v[6]; float mx = -1e30f;
        #pragma unroll
        for (int j = 0; j < 6; ++j) { v[j] = modl[t * 6 + j]; mx = fmaxf(mx, v[j]); }
        float s = 0.f;
        #pragma unroll
        for (int j = 0; j < 6; ++j) { v[j] = __expf(v[j] - mx); s += v[j]; }
        float inv = 1.f / s;
        #pragma unroll
        for (int j = 0; j < 6; ++j) modl[t * 6 + j] = v[j] * inv;
    }
    __syncthreads();

    // ---- mod scaling + phase C (match) ----
    if (t < 16) {
        S.wep0_s[t] *= modl[t * 6 + 2];
        S.wep2_s[t] *= modl[t * 6 + 4];
        S.wdl_s[t]  *= modl[t * 6 + 1];
    }
    for (int i = t; i < 1024; i += 256) wch_s[i] *= modl[(i >> 6) * 6];

    const int my_r = t & 31;
    #pragma unroll 1
    for (int it = 0; it < 2; ++it) {
        int idx = t + 256 * it;
        int p = idx >> 5, r = idx & 31;
        float s0 = bk_s[p], s1 = bk_s[16 + p], s2 = bk_s[32 + p];
        const float4* w0 = (const float4*)(Wk_s + p * 64);
        const float4* w1 = (const float4*)(Wk_s + (16 + p) * 64);
        const float4* w2 = (const float4*)(Wk_s + (32 + p) * 64);
        for (int f4 = 0; f4 < 16; ++f4) {
            float a0[4], a1[4], a2[4];
            *(float4*)a0 = w0[f4]; *(float4*)a1 = w1[f4]; *(float4*)a2 = w2[f4];
            #pragma unroll
            for (int j = 0; j < 4; ++j) {
                int f = f4 * 4 + j;
                float f0 = form_s[f * 33 + r];
                float fm = __shfl_up(f0, 1, 32);   if (r == 0)  fm = 0.f;
                float fp = __shfl_down(f0, 1, 32); if (r == 31) fp = 0.f;
                s0 += a0[j] * fm; s1 += a1[j] * f0; s2 += a2[j] * fp;
            }
        }
        S.match_s[p * 32 + r] = __expf(lsg(s0) + lsg(s1) + lsg(s2));
    }
    __syncthreads();

    // ---- coef + rlI precompute + register caching (before U overlay) ----
    if (t < 96) {
        int sub = t >> 5, r = t & 31;
        const float* w = (sub == 0) ? S.wep0_s : (sub == 1) ? S.wdl_s : S.wep2_s;
        float s = 0.f;
        for (int p = 0; p < 16; ++p) s += S.match_s[p * 32 + r] * w[p];
        float cf;
        if (sub == 1) cf = 1.f - sigm(s - S.sc_s[0]);   // 1 - p_deln
        else          cf = sigm(s - S.sc_s[1]);         // p_epen
        S.coef_s[sub * 32 + r] = cf;
    }
    for (int i = t; i < 512; i += 256) {
        int p = i >> 5, r = i & 31;
        float m = S.match_s[p * 32 + r];
        rlI[2 * i]     = fmaxf(m * S.wep0_s[p], 0.f);
        rlI[2 * i + 1] = fmaxf(m * S.wep2_s[p], 0.f);
    }
    float wchf[16], vchf[16];
    #pragma unroll
    for (int p = 0; p < 16; ++p) {
        wchf[p] = wch_s[p * 64 + f_own];
        vchf[p] = vch_s[p * 64 + f_own];
    }
    const float wncf = S.wnc_s[f_own];
    float si_r[8];                                 // form dies here (U overlay)
    #pragma unroll
    for (int j = 0; j < 8; ++j) si_r[j] = form_s[f_own * 33 + fq * 8 + j];
    __syncthreads();

    // ---- xtab: per-thread fixed f, 8 rs values (overlays U incl. form) ----
    #pragma unroll 1
    for (int j = 0; j < 8; ++j) {
        int rs = fq * 8 + j;                       // wave-uniform
        v2f v02; v02.x = 0.f; v02.y = 0.f;
        float sum = 0.f, vs1 = 0.f;
        const v2f* rlp = (const v2f*)(rlI + 2 * rs);
        #pragma unroll
        for (int p = 0; p < 16; ++p) {
            v2f rl = rlp[p * 32];                  // broadcast b64
            v02 += rl * vepf[p];
            float m = S.match_s[p * 32 + rs];      // broadcast b32
            float wc = m * wchf[p];
            sum += wc;
            vs1 += fmaxf(wc, 0.f) * vchf[p];
        }
        float pch = sigm(sum - wncf);
        float si  = si_r[j];
        xtab[0 * 2048 + rs * 64 + f_own] = v02.x;
        xtab[1 * 2048 + rs * 64 + f_own] = si + pch * (vs1 - si);
        xtab[2 * 2048 + rs * 64 + f_own] = v02.y;
    }
    __syncthreads();

    // ---- k-ordered coefs (k = rs*3+sub) + exclusive prefix (posn) ----
    float* ck_s  = S.match_s;        // match dead after xtab
    float* pos_s = S.match_s + 128;
    if (t < 96) ck_s[t] = S.coef_s[(t % 3) * 32 + (t / 3)];
    __syncthreads();
    if (t < 64) {
        float a = ck_s[t];
        float a0 = a;
        #pragma unroll
        for (int d = 1; d < 64; d <<= 1) { float v = __shfl_up(a, d, 64); if (t >= d) a += v; }
        pos_s[t] = a - a0;                          // exclusive prefix
        float carry = __shfl(a, 63, 64);            // inclusive sum of first 64
        float b2 = (t < 32) ? ck_s[64 + t] : 0.f;
        float c2 = b2;
        #pragma unroll
        for (int d = 1; d < 32; d <<= 1) { float v = __shfl_up(c2, d, 32); if ((t & 31) >= d) c2 += v; }
        if (t < 32) pos_s[64 + t] = carry + c2 - b2;
    }
    __syncthreads();

    // ---- gtab[k][r]: all 96 softmax-gates in parallel (overlays V) ----
    #pragma unroll 1
    for (int i = 0; i < 12; ++i) {
        int idx = t + 256 * i;                      // k = idx>>5, r = idx&31
        int k = idx >> 5, r = idx & 31;
        float posn = pos_s[k];
        float pc = fminf(posn, 31.f);
        float ci = floorf(pc + 0.5f);
        float dmin = posn - ci;
        float dd = posn - (float)r;
        float eo = __expf(-2.f * (dd * dd - dmin * dmin));   // exact, max-subtracted
        float Z = eo;
        Z += __shfl_xor(Z, 1, 32);
        Z += __shfl_xor(Z, 2, 32);
        Z += __shfl_xor(Z, 4, 32);
        Z += __shfl_xor(Z, 8, 32);
        Z += __shfl_xor(Z, 16, 32);
        gtab[idx] = ck_s[k] * eo / Z;
    }
    __syncthreads();

    // ---- phase D: pure-throughput blend ----
    const int fgrp = t >> 5;
    v2f o01, o23, o45, o67;
    o01 = 0.f; o23 = 0.f; o45 = 0.f; o67 = 0.f;
    #pragma unroll 1
    for (int rs = 0; rs < 32; ++rs) {
        #pragma unroll
        for (int sub = 0; sub < 3; ++sub) {
            float g = gtab[(rs * 3 + sub) * 32 + my_r];
            v2f gv; gv.x = g; gv.y = g;
            const float4* xb = (const float4*)(xtab + sub * 2048 + rs * 64 + fgrp * 8);
            float4 xa = xb[0], xc = xb[1];
            v2f x01, x23, x45, x67;
            x01.x = xa.x; x01.y = xa.y; x23.x = xa.z; x23.y = xa.w;
            x45.x = xc.x; x45.y = xc.y; x67.x = xc.z; x67.y = xc.w;
            o01 += gv * (x01 - o01);
            o23 += gv * (x23 - o23);
            o45 += gv * (x45 - o45);
            o67 += gv * (x67 - o67);
        }
    }

    float oreg[8] = {o01.x, o01.y, o23.x, o23.y, o45.x, o45.y, o67.x, o67.y};
    #pragma unroll
    for (int i = 0; i < 8; ++i) {
        ST<F32>(A.outp, b * 2048 + (fgrp * 8 + i) * 32 + my_r, oreg[i]);
    }
}

__global__ __launch_bounds__(256) void scan_kernel(Args A, const float* Y) {
    __shared__ ScanSmem S;
    __shared__ int dt_s;
    const int t = threadIdx.x, b = blockIdx.x;
    int isf32 = probe_is_f32(A.ctx, t, &dt_s);
    if (isf32) scan_body<true>(S, t, b, A, Y);
    else       scan_body<false>(S, t, b, A, Y);
}

// ---------------- Last-resort monolithic fallback (round-2, proven) ---------
struct Smem {
    float U[6144];
    float form_s[64 * 33];
    float match_s[512];
    float wch_s[1024];
    float vch_s[1024];
    float vep0_s[1024];
    float vep2_s[1024];
    float wep0_s[16], wep2_s[16], wdl_s[16];
    float wnc_s[64];
    float sc_s[2];
    float ssum_s[96];
};

template<bool F32>
__device__ void mono_body(Smem& S, int t, int b, const Args& A) {
    float* c_s  = S.U;
    float* modl = S.U + 128;
    float* Wk_s = S.U + 224;
    float* bk_s = S.U + 3344;
    float* xtab = S.U;

    if (t < 128) c_s[t] = LD<F32>(A.ctx, b * 128 + t);
    {
        int e0 = b * 2048 + t * 8;
        float4 x = LD4<F32>(A.form, e0);
        float4 y = LD4<F32>(A.form, e0 + 4);
        int f = t >> 2, r0 = (t & 3) * 8;
        float* dst = S.form_s + f * 33 + r0;
        dst[0] = x.x; dst[1] = x.y; dst[2] = x.z; dst[3] = x.w;
        dst[4] = y.x; dst[5] = y.y; dst[6] = y.z; dst[7] = y.w;
    }
    __syncthreads();
    if (t < 96) {
        float a = LD<F32>(A.mod_b, t);
        for (int cc = 0; cc < 128; ++cc) a += c_s[cc] * LD<F32>(A.mod_W, cc * 96 + t);
        modl[t] = a;
    }
    __syncthreads();
    if (t < 16) {
        float v[6]; float mx = -1e30f;
        #pragma unroll
        for (int j = 0; j < 6; ++j) { v[j] = modl[t * 6 + j]; mx = fmaxf(mx, v[j]); }
        float s = 0.f;
        #pragma unroll
        for (int j = 0; j < 6; ++j) { v[j] = __expf(v[j] - mx); s += v[j]; }
        float inv = 1.f / s;
        #pragma unroll
        for (int j = 0; j < 6; ++j) modl[t * 6 + j] = v[j] * inv;
    }
    __syncthreads();
    for (int j = t; j < 512; j += 256) {
        int n0 = j * 2;
        float2 bb = LD2<F32>(A.wch_b, n0);
        float a0 = bb.x, a1 = bb.y;
        for (int cc = 0; cc < 128; ++cc) {
            float2 w = LD2<F32>(A.wch_W, cc * 1024 + n0); float cv = c_s[cc];
            a0 += cv * w.x; a1 += cv * w.y;
        }
        int p = n0 >> 6; float sc = modl[p * 6 + 0];
        S.wch_s[n0] = sc * a0; S.wch_s[n0 + 1] = sc * a1;
    }
    for (int j = t; j < 512; j += 256) {
        int n0 = j * 2;
        float2 bb = LD2<F32>(A.vch_b, n0);
        float a0 = bb.x, a1 = bb.y;
        for (int cc = 0; cc < 128; ++cc) {
            float2 w = LD2<F32>(A.vch_W, cc * 1024 + n0); float cv = c_s[cc];
            a0 += cv * w.x; a1 += cv * w.y;
        }
        S.vch_s[n0] = a0; S.vch_s[n0 + 1] = a1;
    }
    for (int u = t; u < 1024; u += 256) {
        int n0 = u * 4;
        float4 bb = LD4<F32>(A.vep_b, n0);
        float a0 = bb.x, a2 = bb.z;
        for (int cc = 0; cc < 128; ++cc) {
            float4 w = LD4<F32>(A.vep_W, cc * 4096 + n0); float cv = c_s[cc];
            a0 += cv * w.x; a2 += cv * w.z;
        }
        S.vep0_s[u] = a0; S.vep2_s[u] = a2;
    }
    for (int j = t; j < 1536; j += 256) {
        int k  = j >> 9;
        int jj = j & 511;
        int n0 = jj * 2;
        float2 bb = LD2<F32>(A.m_Wb, k * 1024 + n0);
        float a0 = bb.x, a1 = bb.y;
        for (int cc = 0; cc < 128; ++cc) {
            float2 w = LD2<F32>(A.m_W, (k * 128 + cc) * 1024 + n0); float cv = c_s[cc];
            a0 += cv * w.x; a1 += cv * w.y;
        }
        int p = n0 >> 6, f = n0 & 63;
        Wk_s[(k * 16 + p) * 65 + f]     = a0;
        Wk_s[(k * 16 + p) * 65 + f + 1] = a1;
    }
    if (t < 16) {
        int n0 = t * 4;
        float4 bb = LD4<F32>(A.wep_b, n0);
        float a0 = bb.x, a2 = bb.z;
        for (int cc = 0; cc < 128; ++cc) {
            float4 w = LD4<F32>(A.wep_W, cc * 64 + n0); float cv = c_s[cc];
            a0 += cv * w.x; a2 += cv * w.z;
        }
        S.wep0_s[t] = modl[t * 6 + 2] * a0;
        S.wep2_s[t] = modl[t * 6 + 4] * a2;
    } else if (t < 32) {
        int p = t - 16;
        float a = LD<F32>(A.wdl_b, p);
        for (int cc = 0; cc < 128; ++cc) a += c_s[cc] * LD<F32>(A.wdl_W, cc * 16 + p);
        S.wdl_s[p] = modl[p * 6 + 1] * a;
    } else if (t < 96) {
        int f = t - 32;
        float a = LD<F32>(A.wnc_b, f);
        for (int cc = 0; cc < 128; ++cc) a += c_s[cc] * LD<F32>(A.wnc_W, cc * 64 + f);
        S.wnc_s[f] = __expf(a);
    } else if (t < 98) {
        const void* W  = (t == 96) ? A.wnd_W : A.wne_W;
        const void* bb = (t == 96) ? A.wnd_b : A.wne_b;
        float a = LD<F32>(bb, 0);
        for (int cc = 0; cc < 128; ++cc) a += c_s[cc] * LD<F32>(W, cc);
        S.sc_s[t - 96] = __expf(a);
    } else if (t < 146) {
        int i = t - 98;
        int k = i >> 4, p = i & 15;
        float a = LD<F32>(A.mb_b, k * 16 + p);
        for (int cc = 0; cc < 128; ++cc) a += c_s[cc] * LD<F32>(A.mb_W, (k * 128 + cc) * 16 + p);
        bk_s[i] = a;
    }
    __syncthreads();
    for (int idx = t; idx < 512; idx += 256) {
        int p = idx >> 5, r = idx & 31;
        float s0 = bk_s[p], s1 = bk_s[16 + p], s2 = bk_s[32 + p];
        const float* w0 = Wk_s + p * 65;
        const float* w1 = Wk_s + (16 + p) * 65;
        const float* w2 = Wk_s + (32 + p) * 65;
        for (int f = 0; f < 64; ++f) {
            const float* fr = S.form_s + f * 33 + r;
            float fm1 = (r > 0)  ? fr[-1] : 0.f;
            float f0  = fr[0];
            float fp1 = (r < 31) ? fr[1]  : 0.f;
            s0 += w0[f] * fm1; s1 += w1[f] * f0; s2 += w2[f] * fp1;
        }
        S.match_s[p * 32 + r] = __expf(lsg(s0) + lsg(s1) + lsg(s2));
    }
    __syncthreads();
    if (t < 96) {
        int which = t >> 5, r = t & 31;
        const float* w = (which == 0) ? S.wep0_s : (which == 1) ? S.wep2_s : S.wdl_s;
        float s = 0.f;
        for (int p = 0; p < 16; ++p) s += S.match_s[p * 32 + r] * w[p];
        S.ssum_s[which * 32 + r] = s;
    }
    #pragma unroll 1
    for (int q = 0; q < 24; ++q) {
        int idx = t + 256 * q;
        int sub = idx >> 11;
        int rs  = (idx >> 6) & 31;
        int f   = idx & 63;
        float x;
        if (sub == 1) {
            float sum = 0.f, vs = 0.f;
            for (int p = 0; p < 16; ++p) {
                float wc = S.match_s[p * 32 + rs] * S.wch_s[p * 64 + f];
                sum += wc;
                vs  += fmaxf(wc, 0.f) * S.vch_s[p * 64 + f];
            }
            float pch = sigm(sum - S.wnc_s[f]);
            float si  = S.form_s[f * 33 + rs];
            x = si + pch * (vs - si);
        } else {
            const float* wep = (sub == 0) ? S.wep0_s : S.wep2_s;
            const float* vep = (sub == 0) ? S.vep0_s : S.vep2_s;
            float vs = 0.f;
            for (int p = 0; p < 16; ++p) {
                float w = S.match_s[p * 32 + rs] * wep[p];
                vs += fmaxf(w, 0.f) * vep[p * 64 + f];
            }
            x = vs;
        }
        xtab[idx] = x;
    }
    __syncthreads();
    const int my_r = t & 31;
    const int fgrp = t >> 5;
    float oreg[8];
    #pragma unroll
    for (int i = 0; i < 8; ++i) oreg[i] = 0.f;
    float posn = 0.f;
    const float wnd1v = S.sc_s[0];
    const float wne1v = S.sc_s[1];
    for (int rs = 0; rs < 32; ++rs) {
        #pragma unroll
        for (int sub = 0; sub < 3; ++sub) {
            float coef;
            if (sub == 1) coef = 1.f - sigm(S.ssum_s[64 + rs] - wnd1v);
            else          coef = sigm(S.ssum_s[(sub & 2) * 16 + rs] - wne1v);
            float pc = fminf(posn, 31.f);
            int ci = (int)(pc + 0.5f);
            int lo = ci - 4; if (lo < 0)  lo = 0;
            int hi = ci + 4; if (hi > 31) hi = 31;
            float dmin = posn - (float)ci;
            float mx = -2.f * dmin * dmin;
            float Z = 0.f, eo = 0.f;
            for (int r = lo; r <= hi; ++r) {
                float d = posn - (float)r;
                float e = __expf(-2.f * d * d - mx);
                Z += e;
                if (r == my_r) eo = e;
            }
            float g = coef * eo / Z;
            const float* xb = xtab + (sub * 2048 + rs * 64 + fgrp * 8);
            #pragma unroll
            for (int i = 0; i < 8; ++i) oreg[i] += g * (xb[i] - oreg[i]);
            posn += coef;
        }
    }
    #pragma unroll
    for (int i = 0; i < 8; ++i) {
        ST<F32>(A.outp, b * 2048 + (fgrp * 8 + i) * 32 + my_r, oreg[i]);
    }
}

__global__ __launch_bounds__(256) void phon_mono(Args A) {
    __shared__ Smem S;
    __shared__ int dt_s;
    const int t = threadIdx.x, b = blockIdx.x;
    int isf32 = probe_is_f32(A.ctx, t, &dt_s);
    if (isf32) mono_body<true>(S, t, b, A);
    else       mono_body<false>(S, t, b, A);
}

extern "C" void kernel_launch(void* const* d_in, const int* in_sizes, int n_in,
                              void* d_out, int out_size, void* d_ws, size_t ws_size,
                              hipStream_t stream) {
    Args A;
    A.form  = d_in[0];  A.ctx   = d_in[1];
    A.mod_W = d_in[2];  A.mod_b = d_in[3];
    A.wch_W = d_in[4];  A.wch_b = d_in[5];
    A.wdl_W = d_in[6];  A.wdl_b = d_in[7];
    A.wep_W = d_in[8];  A.wep_b = d_in[9];
    A.vch_W = d_in[10]; A.vch_b = d_in[11];
    A.vep_W = d_in[12]; A.vep_b = d_in[13];
    A.wnc_W = d_in[14]; A.wnc_b = d_in[15];
    A.wnd_W = d_in[16]; A.wnd_b = d_in[17];
    A.wne_W = d_in[18]; A.wne_b = d_in[19];
    A.m_W   = d_in[20]; A.m_Wb  = d_in[21];
    A.mb_W  = d_in[22]; A.mb_b  = d_in[23];
    A.outp  = d_out;

    const size_t needY = (size_t)B_ * YSTRIDE * sizeof(float);
    const size_t needW = needY + ((size_t)128 * WSTRIDE + WSTRIDE) * sizeof(float);
    if (ws_size >= needW) {
        float* Y    = (float*)d_ws;
        float* Wcat = Y + (size_t)B_ * YSTRIDE;
        float* bcat = Wcat + (size_t)128 * WSTRIDE;
        repack_kernel<<<(128 * WSTRIDE / 2) / 256, 256, 0, stream>>>(A, Wcat, bcat);
        gemm4_kernel<<<2048, 256, 0, stream>>>(A, Wcat, bcat, Y);
        scan_kernel<<<B_, 256, 0, stream>>>(A, Y);
    } else if (ws_size >= needY) {
        float* Y = (float*)d_ws;
        gemm_kernel<<<1024, 256, 0, stream>>>(A, Y);
        scan_kernel<<<B_, 256, 0, stream>>>(A, Y);
    } else {
        phon_mono<<<B_, 256, 0, stream>>>(A);
    }
}